// Round 14
// baseline (473.088 us; speedup 1.0000x reference)
//
#include <hip/hip_runtime.h>

// ---------------------------------------------------------------------------
// KPlexPool: GCN -> pools -> matrix-free pooled GCN -> MLP head + softmax
// Sizes: N=100000, E=1600000, F_IN=128, H=128, M=150000, KC=60000, B=64
// R4: scatter-atomics -> device-built CSR gathers.
// R5/R9: bf16 payloads for all re-read intermediates (fp32 accum).
// R7: dense GEMMs -> bf16 MFMA (prepacked W fragments).
// R8/R10/R11: two-level edge fill; class-private cursors; block-aggregated
//   claims (returning-atomic count was the wall).
// R12: quarter-wave row walks (16 lanes x uint4, 4 rows in flight/instr).
// R13/R14: (a) nontemporal stores for bf16-row outputs (via ext_vector u32x4
//   -- HIP uint4 is a struct and rejected by the builtin) + nt loads for
//   epack/slot streams. (b) GEMM epilogue via LDS -> u32x4 nt stores.
//   (c) node_scalars fused into fill_compact. (d) fill_pairs x2 merged.
// ---------------------------------------------------------------------------

#define H 128
#define TILE_AGG 2048
#define GRID_AGG 784     // %8==0; hist_coarse/fill_stage_agg MUST share this

typedef __attribute__((ext_vector_type(4))) float f32x4;
typedef __attribute__((ext_vector_type(8))) short bf16x8;
typedef __attribute__((ext_vector_type(4))) unsigned int u32x4;

__device__ __forceinline__ void atomAddF(float* p, float v) {
    unsafeAtomicAdd(p, v);   // global_atomic_add_f32 on gfx950
}
__device__ __forceinline__ void atomMaxPos(float* p, float v) {
    // valid for non-negative floats (bit pattern order == numeric order)
    atomicMax(reinterpret_cast<int*>(p), __float_as_int(v));
}

// bf16 helpers: RNE pack, shift unpack
__device__ __forceinline__ unsigned int bfr(float f) {
    unsigned int u = __float_as_uint(f);
    return (u + 0x7fffu + ((u >> 16) & 1u)) >> 16;
}
__device__ __forceinline__ unsigned int pk2(float lo, float hi) {
    return bfr(lo) | (bfr(hi) << 16);
}
__device__ __forceinline__ float unlo(unsigned int v) { return __uint_as_float(v << 16); }
__device__ __forceinline__ float unhi(unsigned int v) { return __uint_as_float(v & 0xffff0000u); }

__device__ __forceinline__ void ntstore4(unsigned int a, unsigned int b,
                                         unsigned int c, unsigned int d, void* p) {
    u32x4 v; v.x = a; v.y = b; v.z = c; v.w = d;
    __builtin_nontemporal_store(v, (u32x4*)p);
}

// ========================= CSR build (pairs) ===============================
__global__ void count_pairs(const int* __restrict__ a, const int* __restrict__ b,
                            int* __restrict__ ca, int* __restrict__ cb, int M) {
    int i = blockIdx.x * blockDim.x + threadIdx.x;
    if (i < M) {
        atomicAdd(&ca[__builtin_nontemporal_load(a + i)], 1);
        atomicAdd(&cb[__builtin_nontemporal_load(b + i)], 1);
    }
}

// exclusive scan of c[0..m) in place, 1024 elems/block (used for KC/N arrays)
__global__ __launch_bounds__(256) void scan_partial(const int* __restrict__ c,
                                                    int* __restrict__ part, int m) {
    __shared__ int red[4];
    int base = blockIdx.x * 1024, t = threadIdx.x;
    int s = 0;
    for (int j = t; j < 1024; j += 256) { int i = base + j; if (i < m) s += c[i]; }
    for (int o = 32; o; o >>= 1) s += __shfl_down(s, o, 64);
    if ((t & 63) == 0) red[t >> 6] = s;
    __syncthreads();
    if (t == 0) part[blockIdx.x] = red[0] + red[1] + red[2] + red[3];
}
__global__ void scan_spine(int* part, int G) {
    if (threadIdx.x == 0) {
        int acc = 0;
        for (int i = 0; i < G; ++i) { int v = part[i]; part[i] = acc; acc += v; }
    }
}
__global__ __launch_bounds__(256) void scan_apply(int* __restrict__ c,
                                                  const int* __restrict__ part, int m) {
    __shared__ int wsum[4];
    int base = blockIdx.x * 1024, t = threadIdx.x;
    int i0 = base + t * 4;
    int v0 = 0, v1 = 0, v2 = 0, v3 = 0;
    if (i0     < m) v0 = c[i0];
    if (i0 + 1 < m) v1 = c[i0 + 1];
    if (i0 + 2 < m) v2 = c[i0 + 2];
    if (i0 + 3 < m) v3 = c[i0 + 3];
    int ts = v0 + v1 + v2 + v3;
    int lane = t & 63, w = t >> 6;
    int sc = ts;
    for (int o = 1; o < 64; o <<= 1) { int u = __shfl_up(sc, o, 64); if (lane >= o) sc += u; }
    if (lane == 63) wsum[w] = sc;
    __syncthreads();
    int off = part[blockIdx.x];
    for (int k = 0; k < w; ++k) off += wsum[k];
    int ex = off + sc - ts;
    if (i0     < m) c[i0]     = ex;
    if (i0 + 1 < m) c[i0 + 1] = ex + v0;
    if (i0 + 2 < m) c[i0 + 2] = ex + v0 + v1;
    if (i0 + 3 < m) c[i0 + 3] = ex + v0 + v1 + v2;
}

// both pair CSRs in one pass: pslots (by cluster) + qslots (by node)
__global__ void fill_pairs_both(const int* __restrict__ cclus, const int* __restrict__ cnodes,
                                int* __restrict__ ipoffs, int* __restrict__ iqoffs,
                                int* __restrict__ pslots, int* __restrict__ qslots, int M) {
    int i = blockIdx.x * blockDim.x + threadIdx.x;
    if (i >= M) return;
    int c = __builtin_nontemporal_load(cclus + i);
    int n = __builtin_nontemporal_load(cnodes + i);
    int qp = atomicAdd(&ipoffs[c], 1);
    int qq = atomicAdd(&iqoffs[n], 1);
    pslots[qp] = n;
    qslots[qq] = c;
}

// qcnt[n] = pair count at node n (end-of-row convention offsets)
__global__ void qcnt_kernel(const int* __restrict__ qoffs, int* __restrict__ qcnt, int N) {
    int n = blockIdx.x * blockDim.x + threadIdx.x;
    if (n < N) qcnt[n] = qoffs[n] - (n ? qoffs[n - 1] : 0);
}

// ================= two-level edge fill (block-aggregated claims) ===========
// bucket = dst>>8 (256 nodes); xcd-class = blockIdx&7; cursors class-major
// [x*Ppad+b] (line-private per class). Both kernels iterate tiles with
// IDENTICAL tile->block mapping so counts and claims agree per (bucket,class).
__global__ __launch_bounds__(256) void hist_coarse(const int* __restrict__ dst,
                                                   int* __restrict__ histc, int E, int Ppad) {
    __shared__ int hb[512];   // P <= 512 buckets (N <= 131072)
    for (int i = threadIdx.x; i < 512; i += 256) hb[i] = 0;
    __syncthreads();
    int x = blockIdx.x & 7;
    for (int tile = blockIdx.x; (long)tile * TILE_AGG < E; tile += GRID_AGG) {
        int base = tile * TILE_AGG;
        int lim = min(TILE_AGG, E - base);
        for (int i = threadIdx.x; i < lim; i += 256)
            atomicAdd(&hb[__builtin_nontemporal_load(dst + base + i) >> 8], 1);
    }
    __syncthreads();
    for (int i = threadIdx.x; i < 512; i += 256)
        if (hb[i]) atomicAdd(&histc[x * Ppad + i], hb[i]);
}

// single-block scan over the (bucket,class) histogram (m = P*8 <= 4096):
// reads class-major histc, writes bucket-major exclusive starts (curscan)
// and a class-major copy (curw, the working cursors).
__global__ __launch_bounds__(1024) void scan_small(
    const int* __restrict__ histc, int* __restrict__ curscan,
    int* __restrict__ curw, int P, int Ppad)
{
    __shared__ int wtot[16];
    int t = threadIdx.x;
    int m = P * 8;
    int i0 = t * 4;
    int v[4];
#pragma unroll
    for (int k = 0; k < 4; ++k) {
        int id = i0 + k;
        v[k] = (id < m) ? histc[(id & 7) * Ppad + (id >> 3)] : 0;
    }
    int ts = v[0] + v[1] + v[2] + v[3];
    int lane = t & 63, w = t >> 6;
    int sc = ts;
    for (int o = 1; o < 64; o <<= 1) { int u = __shfl_up(sc, o, 64); if (lane >= o) sc += u; }
    if (lane == 63) wtot[w] = sc;
    __syncthreads();
    int off = 0;
    for (int k = 0; k < w; ++k) off += wtot[k];
    int ex = off + sc - ts;
#pragma unroll
    for (int k = 0; k < 4; ++k) {
        int id = i0 + k;
        if (id < m) {
            curscan[id] = ex;
            curw[(id & 7) * Ppad + (id >> 3)] = ex;
        }
        ex += v[k];
    }
}

// stage, block-aggregated: per 2048-edge tile, LDS bucket histogram ->
// ONE returning atomic per (bucket,tile) claims a contiguous run ->
// scatter each edge at gbase[b] + LDS-rank. dloc packed in src bits 20..27.
__global__ __launch_bounds__(256) void fill_stage_agg(
    const int* __restrict__ src, const int* __restrict__ dst,
    const float* __restrict__ w, int* __restrict__ cur,
    int2* __restrict__ stg, int E, int Ppad)
{
    __shared__ int cnt[512];
    __shared__ int gbase[512];
    int t = threadIdx.x;
    int x = blockIdx.x & 7;
    for (int tile = blockIdx.x; (long)tile * TILE_AGG < E; tile += GRID_AGG) {
        int base = tile * TILE_AGG;
        int lim = min(TILE_AGG, E - base);
        for (int i = t; i < 512; i += 256) cnt[i] = 0;
        __syncthreads();
        for (int i = t; i < lim; i += 256)
            atomicAdd(&cnt[__builtin_nontemporal_load(dst + base + i) >> 8], 1);
        __syncthreads();
        for (int b = t; b < 512; b += 256) {
            int c = cnt[b];
            if (c) gbase[b] = atomicAdd(&cur[x * Ppad + b], c);
        }
        __syncthreads();
        for (int i = t; i < 512; i += 256) cnt[i] = 0;
        __syncthreads();
        for (int i = t; i < lim; i += 256) {
            int d  = __builtin_nontemporal_load(dst + base + i);
            int s  = __builtin_nontemporal_load(src + base + i);
            float wv = __builtin_nontemporal_load(w + base + i);
            int b = d >> 8;
            int r = atomicAdd(&cnt[b], 1);
            stg[gbase[b] + r] = make_int2(s | ((d & 255) << 20), __float_as_int(wv));
        }
        __syncthreads();   // protect cnt/gbase before next tile's reset
    }
}

// compact: one block owns one bucket's contiguous region [gs,ge).
// FUSED node_scalars: accumulates degw and ye1 per node via LDS float
// atomics during the count pass (qcnt must be ready), writes dinv/ye1.
__global__ __launch_bounds__(1024) void fill_compact(
    const int* __restrict__ curscan, const int2* __restrict__ stg,
    int2* __restrict__ epack, int* __restrict__ ieoffs,
    const int* __restrict__ qcnt, float* __restrict__ dinv,
    float* __restrict__ ye1, int E, int N, int P)
{
    __shared__ int cnt[256];
    __shared__ float degw[256];
    __shared__ float ysum[256];
    __shared__ int wsum[4];
    int b = blockIdx.x, t = threadIdx.x;
    int gs = curscan[b * 8];
    int ge = (b == P - 1) ? E : curscan[(b + 1) * 8];
    if (t < 256) { cnt[t] = 0; degw[t] = 0.f; ysum[t] = 0.f; }
    __syncthreads();
    for (int i = gs + t; i < ge; i += 1024) {
        int2 pv = stg[i];
        int dloc = (pv.x >> 20) & 255;
        int s = pv.x & 0xFFFFF;
        float w = __int_as_float(pv.y);
        atomicAdd(&cnt[dloc], 1);
        atomicAdd(&degw[dloc], w);
        atomicAdd(&ysum[dloc], w * (float)qcnt[s]);
    }
    __syncthreads();
    int v = 0, sc = 0;
    if (t < 256) {                       // waves 0-3 entirely inside
        v = cnt[t];
        int lane = t & 63;
        sc = v;
        for (int o = 1; o < 64; o <<= 1) { int u = __shfl_up(sc, o, 64); if (lane >= o) sc += u; }
        if (lane == 63) wsum[t >> 6] = sc;
    }
    __syncthreads();
    if (t < 256) {
        int off = 0;
        for (int k = 0; k < (t >> 6); ++k) off += wsum[k];
        int excl = off + sc - v;         // exclusive prefix within bucket
        int node = b * 256 + t;
        if (node < N) {
            ieoffs[node] = gs + excl + v;   // end-of-row
            dinv[node] = rsqrtf(degw[t] + 1.0f);
            ye1[node] = ysum[t];
        }
        cnt[t] = excl;                   // reuse as per-node cursor
    }
    __syncthreads();
    for (int i = gs + t; i < ge; i += 1024) {
        int2 pv = stg[i];
        int pos = atomicAdd(&cnt[(pv.x >> 20) & 255], 1);
        epack[gs + pos] = make_int2(pv.x & 0xFFFFF, pv.y);
    }
}

__global__ void cluster_dinvp(const int* __restrict__ poffs, const int* __restrict__ pslots,
                              const float* __restrict__ ye1, float* __restrict__ dinvp, int KC) {
    int c = blockIdx.x * blockDim.x + threadIdx.x;
    if (c >= KC) return;
    int b = c ? poffs[c - 1] : 0, e = poffs[c];
    float s = 0.f;
    for (int i = b; i < e; ++i) s += ye1[pslots[i]];
    dinvp[c] = rsqrtf(s + 1.0f);
}

// ========================= MFMA GEMM (bf16 in, fp32 accum) =================
template <int KSTEPS>
__global__ void prepack_w(const float* __restrict__ W, uint4* __restrict__ wp) {
    int idx = blockIdx.x * blockDim.x + threadIdx.x;   // frag-lane id
    if (idx >= 8 * KSTEPS * 64) return;
    int l = idx & 63;
    int f = idx >> 6;                 // ct*KSTEPS + kb
    int kb = f % KSTEPS, ct = f / KSTEPS;
    int col = ct * 16 + (l & 15);
    int k0 = kb * 32 + (l >> 4) * 8;
    uint4 u;
    u.x = pk2(W[(k0 + 0) * 128 + col], W[(k0 + 1) * 128 + col]);
    u.y = pk2(W[(k0 + 2) * 128 + col], W[(k0 + 3) * 128 + col]);
    u.z = pk2(W[(k0 + 4) * 128 + col], W[(k0 + 5) * 128 + col]);
    u.w = pk2(W[(k0 + 6) * 128 + col], W[(k0 + 7) * 128 + col]);
    wp[idx] = u;
}

// shared epilogue: stage bf16 C-tile to LDS, cooperative u32x4 nt stores.
// Sl: ushort[64][128] (16KB) overlapping the W buffer (post-sync reuse).
__device__ __forceinline__ void gemm_epilogue(
    unsigned short* Sl, f32x4 (&acc)[8], const float* rowscale,
    unsigned short* outb, int nrows, int t, int l, int wv, int row0)
{
    int rbase = row0 + (l >> 4) * 4;
    float sc[4];
#pragma unroll
    for (int g = 0; g < 4; ++g)
        sc[g] = rowscale ? (rbase + g < nrows ? rowscale[rbase + g] : 1.f) : 1.f;
    int lr = wv * 16 + (l >> 4) * 4;   // local row base
#pragma unroll
    for (int ct = 0; ct < 8; ++ct) {
        int col = ct * 16 + (l & 15);
#pragma unroll
        for (int g = 0; g < 4; ++g)
            Sl[(lr + g) * 128 + col] = (unsigned short)bfr(acc[ct][g] * sc[g]);
    }
    __syncthreads();
    long rowbase = (long)(row0 - wv * 16);   // = blockIdx.x * 64
    u32x4* out4 = (u32x4*)outb;
    const u32x4* S4 = (const u32x4*)Sl;
    for (int idx = t; idx < 64 * 16; idx += 256) {
        long gr = rowbase + (idx >> 4);
        if (gr < nrows)
            __builtin_nontemporal_store(S4[idx], &out4[gr * 16 + (idx & 15)]);
    }
}

// fp32-A variant (used for x @ Win), bf16 out.
template <int KSTEPS>
__global__ __launch_bounds__(256) void gemm_mfma(
    const float* __restrict__ XA,
    const uint4* __restrict__ wpack, const float* __restrict__ rowscale,
    unsigned short* __restrict__ outb, int nrows)
{
    __shared__ uint4 Wl[8 * KSTEPS * 64];
    int t = threadIdx.x;
    for (int i = t; i < 8 * KSTEPS * 64; i += 256) Wl[i] = wpack[i];
    __syncthreads();

    int l = t & 63, wv = t >> 6;
    int row0 = blockIdx.x * 64 + wv * 16;
    int rr = row0 + (l & 15);
    long rc = (rr < nrows ? rr : nrows - 1);
    int kq = (l >> 4) * 8;

    f32x4 acc[8];
#pragma unroll
    for (int ct = 0; ct < 8; ++ct) acc[ct] = (f32x4)0.f;

#pragma unroll
    for (int kb = 0; kb < KSTEPS; ++kb) {
        const float* p = XA + rc * 128 + kb * 32 + kq;
        float4 a0 = ((const float4*)p)[0];
        float4 a1 = ((const float4*)p)[1];
        union { uint4 u; bf16x8 v; } af;
        af.u.x = pk2(a0.x, a0.y); af.u.y = pk2(a0.z, a0.w);
        af.u.z = pk2(a1.x, a1.y); af.u.w = pk2(a1.z, a1.w);
#pragma unroll
        for (int ct = 0; ct < 8; ++ct) {
            union { uint4 u; bf16x8 v; } bf;
            bf.u = Wl[(ct * KSTEPS + kb) * 64 + l];
            acc[ct] = __builtin_amdgcn_mfma_f32_16x16x32_bf16(af.v, bf.v, acc[ct], 0, 0, 0);
        }
    }
    __syncthreads();   // done with Wl; reuse as bf16 staging
    gemm_epilogue((unsigned short*)Wl, acc, rowscale, outb, nrows, t, l, wv, row0);
}

// bf16-A variant, K=256 over two bf16 matrices (xadd rows || xmax rows).
__global__ __launch_bounds__(256) void gemm_mfma_bfA(
    const uint4* __restrict__ XA, const uint4* __restrict__ XB,
    const uint4* __restrict__ wpack, const float* __restrict__ rowscale,
    unsigned short* __restrict__ outb, int nrows)
{
    __shared__ uint4 Wl[8 * 8 * 64];
    int t = threadIdx.x;
    for (int i = t; i < 4096; i += 256) Wl[i] = wpack[i];
    __syncthreads();

    int l = t & 63, wv = t >> 6;
    int row0 = blockIdx.x * 64 + wv * 16;
    int rr = row0 + (l & 15);
    long rc = (rr < nrows ? rr : nrows - 1);
    int kq8 = (l >> 4);            // kq/8, 0..3

    f32x4 acc[8];
#pragma unroll
    for (int ct = 0; ct < 8; ++ct) acc[ct] = (f32x4)0.f;

#pragma unroll
    for (int kb = 0; kb < 8; ++kb) {
        const uint4* s = (kb >= 4) ? XB : XA;
        union { uint4 u; bf16x8 v; } af;
        af.u = s[rc * 16 + (kb & 3) * 4 + kq8];   // bf16 row = 16 uint4
#pragma unroll
        for (int ct = 0; ct < 8; ++ct) {
            union { uint4 u; bf16x8 v; } bf;
            bf.u = Wl[(ct * 8 + kb) * 64 + l];
            acc[ct] = __builtin_amdgcn_mfma_f32_16x16x32_bf16(af.v, bf.v, acc[ct], 0, 0, 0);
        }
    }
    __syncthreads();
    gemm_epilogue((unsigned short*)Wl, acc, rowscale, outb, nrows, t, l, wv, row0);
}

// ========================= vector CSR gathers (quarter-wave) ===============
// bf16 row = 256B = 16 lanes x uint4; 4 edges in flight per load instr.

// GCN pass 1, fused: h[n] = relu(dinv_n*(sum w*dinv_s*xw[s] + dinv_n*xw[n]) + b)
__global__ __launch_bounds__(256) void gcn1_gather(
    const int* __restrict__ eoffs, const long long* __restrict__ epack,
    const float* __restrict__ dinv, const uint4* __restrict__ X4,
    const float* __restrict__ bin, uint4* __restrict__ H4, int N)
{
    int n = blockIdx.x * 4 + (threadIdx.x >> 6);
    if (n >= N) return;
    int lane = threadIdx.x & 63;
    int ql = lane & 15, grp = lane >> 4;
    int b = n ? eoffs[n - 1] : 0, e = eoffs[n];
    float4 a0 = make_float4(0.f, 0.f, 0.f, 0.f), a1 = a0;
    for (int i = b; i < e; i += 64) {
        int cnt = min(64, e - i);
        int s_l = 0; float sc_l = 0.f;
        if (lane < cnt) {
            long long pk8 = __builtin_nontemporal_load(epack + i + lane);
            s_l = (int)(pk8 & 0xffffffff);
            sc_l = __int_as_float((int)(pk8 >> 32)) * dinv[s_l];
        }
        int steps = (cnt + 3) >> 2;
#pragma unroll 2
        for (int j = 0; j < steps; ++j) {
            int idx = 4 * j + grp;            // sc==0 for idx>=cnt (tail)
            int s = __shfl(s_l, idx, 64);
            float sc = __shfl(sc_l, idx, 64);
            uint4 v = X4[(unsigned)s * 16u + ql];
            a0.x += sc * unlo(v.x); a0.y += sc * unhi(v.x);
            a0.z += sc * unlo(v.y); a0.w += sc * unhi(v.y);
            a1.x += sc * unlo(v.z); a1.y += sc * unhi(v.z);
            a1.z += sc * unlo(v.w); a1.w += sc * unhi(v.w);
        }
    }
#pragma unroll
    for (int o = 16; o <= 32; o <<= 1) {
        a0.x += __shfl_xor(a0.x, o, 64); a0.y += __shfl_xor(a0.y, o, 64);
        a0.z += __shfl_xor(a0.z, o, 64); a0.w += __shfl_xor(a0.w, o, 64);
        a1.x += __shfl_xor(a1.x, o, 64); a1.y += __shfl_xor(a1.y, o, 64);
        a1.z += __shfl_xor(a1.z, o, 64); a1.w += __shfl_xor(a1.w, o, 64);
    }
    if (grp == 0) {
        float dd = dinv[n];
        uint4 sv = X4[(unsigned)n * 16u + ql];
        float4 b0 = ((const float4*)bin)[ql * 2];
        float4 b1 = ((const float4*)bin)[ql * 2 + 1];
        float o0 = fmaxf(dd * (a0.x + dd * unlo(sv.x)) + b0.x, 0.f);
        float o1 = fmaxf(dd * (a0.y + dd * unhi(sv.x)) + b0.y, 0.f);
        float o2 = fmaxf(dd * (a0.z + dd * unlo(sv.y)) + b0.z, 0.f);
        float o3 = fmaxf(dd * (a0.w + dd * unhi(sv.y)) + b0.w, 0.f);
        float o4 = fmaxf(dd * (a1.x + dd * unlo(sv.z)) + b1.x, 0.f);
        float o5 = fmaxf(dd * (a1.y + dd * unhi(sv.z)) + b1.y, 0.f);
        float o6 = fmaxf(dd * (a1.z + dd * unlo(sv.w)) + b1.z, 0.f);
        float o7 = fmaxf(dd * (a1.w + dd * unhi(sv.w)) + b1.w, 0.f);
        ntstore4(pk2(o0, o1), pk2(o2, o3), pk2(o4, o5), pk2(o6, o7),
                 &H4[(long)n * 16 + ql]);
    }
}

// plain edge gather from bf16 rows: Out[n] = sum_e w * X[src]  (bf16 out)
__global__ __launch_bounds__(256) void edge_gather_plain(
    const int* __restrict__ eoffs, const long long* __restrict__ epack,
    const uint4* __restrict__ X4, uint4* __restrict__ Out4, int N)
{
    int n = blockIdx.x * 4 + (threadIdx.x >> 6);
    if (n >= N) return;
    int lane = threadIdx.x & 63;
    int ql = lane & 15, grp = lane >> 4;
    int b = n ? eoffs[n - 1] : 0, e = eoffs[n];
    float4 a0 = make_float4(0.f, 0.f, 0.f, 0.f), a1 = a0;
    for (int i = b; i < e; i += 64) {
        int cnt = min(64, e - i);
        int s_l = 0; float sc_l = 0.f;
        if (lane < cnt) {
            long long pk8 = __builtin_nontemporal_load(epack + i + lane);
            s_l = (int)(pk8 & 0xffffffff);
            sc_l = __int_as_float((int)(pk8 >> 32));
        }
        int steps = (cnt + 3) >> 2;
#pragma unroll 2
        for (int j = 0; j < steps; ++j) {
            int idx = 4 * j + grp;
            int s = __shfl(s_l, idx, 64);
            float sc = __shfl(sc_l, idx, 64);
            uint4 v = X4[(unsigned)s * 16u + ql];
            a0.x += sc * unlo(v.x); a0.y += sc * unhi(v.x);
            a0.z += sc * unlo(v.y); a0.w += sc * unhi(v.y);
            a1.x += sc * unlo(v.z); a1.y += sc * unhi(v.z);
            a1.z += sc * unlo(v.w); a1.w += sc * unhi(v.w);
        }
    }
#pragma unroll
    for (int o = 16; o <= 32; o <<= 1) {
        a0.x += __shfl_xor(a0.x, o, 64); a0.y += __shfl_xor(a0.y, o, 64);
        a0.z += __shfl_xor(a0.z, o, 64); a0.w += __shfl_xor(a0.w, o, 64);
        a1.x += __shfl_xor(a1.x, o, 64); a1.y += __shfl_xor(a1.y, o, 64);
        a1.z += __shfl_xor(a1.z, o, 64); a1.w += __shfl_xor(a1.w, o, 64);
    }
    if (grp == 0)
        ntstore4(pk2(a0.x, a0.y), pk2(a0.z, a0.w), pk2(a1.x, a1.y), pk2(a1.z, a1.w),
                 &Out4[(long)n * 16 + ql]);
}

// cover pool: x_add[c] = sum h[node], x_max[c] = max h[node]  (bf16 in/out)
__global__ __launch_bounds__(256) void cover_pool(
    const int* __restrict__ poffs, const int* __restrict__ pslots,
    const uint4* __restrict__ H4, uint4* __restrict__ xadd,
    uint4* __restrict__ xmax, int KC)
{
    int c = blockIdx.x * 16 + (threadIdx.x >> 4);
    if (c >= KC) return;
    int ql = threadIdx.x & 15;
    int b = c ? poffs[c - 1] : 0, e = poffs[c];
    float4 s0 = make_float4(0.f, 0.f, 0.f, 0.f), s1 = s0, m0 = s0, m1 = s0;
#pragma unroll 2
    for (int i = b; i < e; ++i) {
        uint4 v = H4[(unsigned)__builtin_nontemporal_load(pslots + i) * 16u + ql];
        float e0 = unlo(v.x), e1 = unhi(v.x), e2 = unlo(v.y), e3 = unhi(v.y);
        float e4 = unlo(v.z), e5 = unhi(v.z), e6 = unlo(v.w), e7 = unhi(v.w);
        s0.x += e0; s0.y += e1; s0.z += e2; s0.w += e3;
        s1.x += e4; s1.y += e5; s1.z += e6; s1.w += e7;
        m0.x = fmaxf(m0.x, e0); m0.y = fmaxf(m0.y, e1);
        m0.z = fmaxf(m0.z, e2); m0.w = fmaxf(m0.w, e3);
        m1.x = fmaxf(m1.x, e4); m1.y = fmaxf(m1.y, e5);
        m1.z = fmaxf(m1.z, e6); m1.w = fmaxf(m1.w, e7);
    }
    ntstore4(pk2(s0.x, s0.y), pk2(s0.z, s0.w), pk2(s1.x, s1.y), pk2(s1.z, s1.w),
             &xadd[(long)c * 16 + ql]);
    ntstore4(pk2(m0.x, m0.y), pk2(m0.z, m0.w), pk2(m1.x, m1.y), pk2(m1.z, m1.w),
             &xmax[(long)c * 16 + ql]);
}

// zn[n] = sum_{p at node n} xws[cluster_p]   (bf16 in/out, fp32 accum)
__global__ __launch_bounds__(256) void zn_gather(
    const int* __restrict__ qoffs, const int* __restrict__ qslots,
    const uint4* __restrict__ X4, uint4* __restrict__ Z4, int N)
{
    int n = blockIdx.x * 16 + (threadIdx.x >> 4);
    if (n >= N) return;
    int ql = threadIdx.x & 15;
    int b = n ? qoffs[n - 1] : 0, e = qoffs[n];
    float4 a0 = make_float4(0.f, 0.f, 0.f, 0.f), a1 = a0;
#pragma unroll 2
    for (int i = b; i < e; ++i) {
        uint4 v = X4[(unsigned)__builtin_nontemporal_load(qslots + i) * 16u + ql];
        a0.x += unlo(v.x); a0.y += unhi(v.x); a0.z += unlo(v.y); a0.w += unhi(v.y);
        a1.x += unlo(v.z); a1.y += unhi(v.z); a1.z += unlo(v.w); a1.w += unhi(v.w);
    }
    ntstore4(pk2(a0.x, a0.y), pk2(a0.z, a0.w), pk2(a1.x, a1.y), pk2(a1.z, a1.w),
             &Z4[(long)n * 16 + ql]);
}

// hp[c] = relu(dinvp_c * (sum_{p in c} ye[node_p] + xws[c]) + b_blk)
__global__ __launch_bounds__(256) void aphp_gather(
    const int* __restrict__ poffs, const int* __restrict__ pslots,
    const uint4* __restrict__ Y4, const uint4* __restrict__ xws4,
    const float* __restrict__ dinvp, const float* __restrict__ bblk,
    uint4* __restrict__ hp4, int KC)
{
    int c = blockIdx.x * 16 + (threadIdx.x >> 4);
    if (c >= KC) return;
    int ql = threadIdx.x & 15;
    int b = c ? poffs[c - 1] : 0, e = poffs[c];
    float4 a0 = make_float4(0.f, 0.f, 0.f, 0.f), a1 = a0;
#pragma unroll 2
    for (int i = b; i < e; ++i) {
        uint4 v = Y4[(unsigned)__builtin_nontemporal_load(pslots + i) * 16u + ql];
        a0.x += unlo(v.x); a0.y += unhi(v.x); a0.z += unlo(v.y); a0.w += unhi(v.y);
        a1.x += unlo(v.z); a1.y += unhi(v.z); a1.z += unlo(v.w); a1.w += unhi(v.w);
    }
    float d = dinvp[c];
    uint4 xv = xws4[(long)c * 16 + ql];
    float4 b0 = ((const float4*)bblk)[ql * 2];
    float4 b1 = ((const float4*)bblk)[ql * 2 + 1];
    float o0 = fmaxf(d * (a0.x + unlo(xv.x)) + b0.x, 0.f);
    float o1 = fmaxf(d * (a0.y + unhi(xv.x)) + b0.y, 0.f);
    float o2 = fmaxf(d * (a0.z + unlo(xv.y)) + b0.z, 0.f);
    float o3 = fmaxf(d * (a0.w + unhi(xv.y)) + b0.w, 0.f);
    float o4 = fmaxf(d * (a1.x + unlo(xv.z)) + b1.x, 0.f);
    float o5 = fmaxf(d * (a1.y + unhi(xv.z)) + b1.y, 0.f);
    float o6 = fmaxf(d * (a1.z + unlo(xv.w)) + b1.z, 0.f);
    float o7 = fmaxf(d * (a1.w + unhi(xv.w)) + b1.w, 0.f);
    ntstore4(pk2(o0, o1), pk2(o2, o3), pk2(o4, o5), pk2(o6, o7),
             &hp4[(long)c * 16 + ql]);
}

// ========================= batch pools + head ==============================
__global__ __launch_bounds__(128) void seg_pool_bf(
    const unsigned short* __restrict__ X, const int* __restrict__ seg,
    float* __restrict__ Z, int n, int sumoff, int maxoff)
{
    int j = threadIdx.x;
    long beg = (long)blockIdx.x * n / gridDim.x;
    long end = (long)(blockIdx.x + 1) * n / gridDim.x;
    if (beg >= end) return;
    int curb = seg[beg];
    float s = 0.f, mx = 0.f;
    for (long i = beg; i < end; ++i) {
        int b = seg[i];
        if (b != curb) {
            atomAddF(&Z[(long)curb * 512 + sumoff + j], s);
            atomMaxPos(&Z[(long)curb * 512 + maxoff + j], mx);
            s = 0.f; mx = 0.f; curb = b;
        }
        float v = __uint_as_float((unsigned int)X[i * (long)H + j] << 16);
        s += v; mx = fmaxf(mx, v);
    }
    atomAddF(&Z[(long)curb * 512 + sumoff + j], s);
    atomMaxPos(&Z[(long)curb * 512 + maxoff + j], mx);
}

__global__ void hist64(const int* __restrict__ seg, float* __restrict__ cc, int n) {
    __shared__ int hc[128];
    if (threadIdx.x < 128) hc[threadIdx.x] = 0;
    __syncthreads();
    for (int i = blockIdx.x * blockDim.x + threadIdx.x; i < n; i += gridDim.x * blockDim.x)
        atomicAdd(&hc[seg[i]], 1);
    __syncthreads();
    if (threadIdx.x < 128 && hc[threadIdx.x] != 0)
        atomAddF(&cc[threadIdx.x], (float)hc[threadIdx.x]);
}

__global__ __launch_bounds__(128) void head_kernel(
    const float* __restrict__ z, const float* __restrict__ cc,
    const float* __restrict__ gamma, const float* __restrict__ beta,
    const float* __restrict__ bmean, const float* __restrict__ bvar,
    const float* __restrict__ W1, const float* __restrict__ b1,
    const float* __restrict__ W2, const float* __restrict__ b2,
    float* __restrict__ out)
{
    __shared__ float zb[512];
    __shared__ float z1[128];
    __shared__ float lg[10];
    __shared__ float red[2];
    int b = blockIdx.x, t = threadIdx.x;
    float ccb = cc[b];
    for (int k = t; k < 512; k += 128) {
        float v = z[(long)b * 512 + k];
        if (k >= 256 && k < 384) v /= ccb;
        v = (v - bmean[k]) * rsqrtf(bvar[k] + 1e-5f) * gamma[k] + beta[k];
        zb[k] = v;
    }
    __syncthreads();
    float acc = b1[t];
    for (int k = 0; k < 512; ++k) acc += zb[k] * W1[k * 128 + t];
    z1[t] = fmaxf(acc, 0.f);
    __syncthreads();
    if (t < 10) {
        float a = b2[t];
        for (int k = 0; k < 128; ++k) a += z1[k] * W2[k * 10 + t];
        lg[t] = a;
    }
    __syncthreads();
    if (t == 0) {
        float m = lg[0];
        for (int i = 1; i < 10; ++i) m = fmaxf(m, lg[i]);
        float s = 0.f;
        for (int i = 0; i < 10; ++i) s += expf(lg[i] - m);
        red[0] = m; red[1] = s;
    }
    __syncthreads();
    if (t < 10) out[(long)b * 10 + t] = expf(lg[t] - red[0]) / red[1];
}

// ---------------------------------------------------------------------------
static void scan_ex(int* buf, int m, int* part, hipStream_t s) {
    int G = (m + 1023) / 1024;
    scan_partial<<<G, 256, 0, s>>>(buf, part, m);
    scan_spine<<<1, 64, 0, s>>>(part, G);
    scan_apply<<<G, 256, 0, s>>>(buf, part, m);
}

extern "C" void kernel_launch(void* const* d_in, const int* in_sizes, int n_in,
                              void* d_out, int out_size, void* d_ws, size_t ws_size,
                              hipStream_t stream)
{
    const float* x      = (const float*)d_in[0];
    const int*   ei     = (const int*)  d_in[1];
    const float* wts    = (const float*)d_in[2];
    const int*   batch  = (const int*)  d_in[3];
    const int*   cnodes = (const int*)  d_in[4];
    const int*   cclus  = (const int*)  d_in[5];
    const int*   cbatch = (const int*)  d_in[6];
    const float* Win    = (const float*)d_in[7];
    const float* bin    = (const float*)d_in[8];
    const float* Wblk   = (const float*)d_in[9];
    const float* bblk   = (const float*)d_in[10];
    const float* gma    = (const float*)d_in[11];
    const float* bta    = (const float*)d_in[12];
    const float* bmean  = (const float*)d_in[13];
    const float* bvar   = (const float*)d_in[14];
    const float* W1     = (const float*)d_in[15];
    const float* b1     = (const float*)d_in[16];
    const float* W2     = (const float*)d_in[17];
    const float* b2     = (const float*)d_in[18];
    float* out = (float*)d_out;

    const int N  = in_sizes[0] / H;
    const int E  = in_sizes[1] / 2;
    const int M  = in_sizes[4];
    const int KC = in_sizes[6];
    const int Bq = out_size / 10;
    const int P  = (N + 255) >> 8;       // coarse buckets (256 nodes), <=512
    const int Ppad = (P + 15) & ~15;     // class stride, whole 64B lines

    const int* src = ei;
    const int* dst = ei + E;

    const long NH = (long)N * H;
    const long KH = (long)KC * H;

    // ---- workspace layout (wpack first for 16B alignment) ----
    float* ws     = (float*)d_ws;
    uint4* wpackN = (uint4*)ws;                     // 2048 uint4 (32KB)
    uint4* wpackK = wpackN + 2048;                  // 4096 uint4 (64KB)
    unsigned int* Abf = (unsigned int*)(wpackK + 4096); // xw -> zn bf16 [NH/2]
    unsigned int* Hbf = Abf + NH / 2;               // h bf16 -> ye bf16 [NH/2]
    unsigned int* Cbf = Hbf + NH / 2;               // xws bf16          [KH/2]
    unsigned int* Fadd= Cbf + KH / 2;               // x_add bf16 -> hp  [KH/2]
    unsigned int* Fmax= Fadd + KH / 2;              // x_max bf16        [KH/2]
    float* dinv = (float*)(Fmax + KH / 2);          //                   [N]
    float* ye1  = dinv + N;                         //                   [N]
    float* dinvp= ye1 + N;                          //                   [KC]
    float* z    = dinvp + KC;                       // pooled features   [Bq*512]
    float* cc   = z + (long)Bq * 512;               // cluster counts    [Bq]
    int* ieoffs = (int*)(cc + Bq);    // edge CSR offsets (dst)  [N]
    int* ipoffs = ieoffs + N;         // pair CSR by cluster     [KC]
    int* iqoffs = ipoffs + KC;        // pair CSR by node        [N]
    int* epack  = iqoffs + N;         // {src, w} per edge slot  [2E]
    int* pslots = epack + 2L * E;     // node per cluster-slot   [M]
    int* qslots = pslots + M;         // cluster per node-slot   [M]
    int* spart  = qslots + M;         // scan partials           [2048]
    int* curscan= spart + 2048;       // bucket-major starts     [P*8]
    int* histc  = curscan + P * 8;    // class-major hist        [8*Ppad]
    int* curw   = histc + 8 * Ppad;   // class-major cursors     [8*Ppad]
    int* qcnt   = curw + 8 * Ppad;    // pairs per node          [N]
    int2* estg  = (int2*)(qcnt + N);  // staged edges            [E]

    // ---- 1. pair CSRs first (qcnt feeds the fused edge compact) ----
    hipMemsetAsync(ipoffs, 0, ((long)KC + N) * sizeof(int), stream);
    count_pairs<<<(M + 255) / 256, 256, 0, stream>>>(cclus, cnodes, ipoffs, iqoffs, M);
    scan_ex(ipoffs, KC, spart, stream);
    scan_ex(iqoffs, N, spart, stream);
    fill_pairs_both<<<(M + 255) / 256, 256, 0, stream>>>(cclus, cnodes, ipoffs, iqoffs,
                                                         pslots, qslots, M);
    qcnt_kernel<<<(N + 255) / 256, 256, 0, stream>>>(iqoffs, qcnt, N);

    // ---- 2. edge CSR: block-aggregated fill + fused node scalars ----
    hipMemsetAsync(histc, 0, 8 * Ppad * sizeof(int), stream);
    hist_coarse<<<GRID_AGG, 256, 0, stream>>>(dst, histc, E, Ppad);
    scan_small<<<1, 1024, 0, stream>>>(histc, curscan, curw, P, Ppad);
    fill_stage_agg<<<GRID_AGG, 256, 0, stream>>>(src, dst, wts, curw, estg, E, Ppad);
    fill_compact<<<P, 1024, 0, stream>>>(curscan, estg, (int2*)epack, ieoffs,
                                         qcnt, dinv, ye1, E, N, P);
    cluster_dinvp<<<(KC + 255) / 256, 256, 0, stream>>>(ipoffs, pslots, ye1, dinvp, KC);

    // ---- 0. prepack weights into MFMA fragment order (bf16) ----
    prepack_w<4><<<8, 256, 0, stream>>>(Win, wpackN);
    prepack_w<8><<<16, 256, 0, stream>>>(Wblk, wpackK);

    // ---- 3. conv_in (fused): xw = x@Win (bf16 MFMA), gather+relu -> h bf16 ----
    gemm_mfma<4><<<(N + 63) / 64, 256, 0, stream>>>(x, wpackN, nullptr,
                                                    (unsigned short*)Abf, N);
    gcn1_gather<<<(N + 3) / 4, 256, 0, stream>>>(ieoffs, (const long long*)epack, dinv,
                                                 (const uint4*)Abf, bin,
                                                 (uint4*)Hbf, N);

    // ---- 4. pools of h (bf16) ----
    hipMemsetAsync(z, 0, ((long)Bq * 512 + Bq) * sizeof(float), stream);
    cover_pool<<<(KC + 15) / 16, 256, 0, stream>>>(ipoffs, pslots, (const uint4*)Hbf,
                                                   (uint4*)Fadd, (uint4*)Fmax, KC);
    seg_pool_bf<<<1024, 128, 0, stream>>>((const unsigned short*)Hbf, batch, z, N, 0, 128);
    hist64<<<256, 256, 0, stream>>>(cbatch, cc, KC);

    // ---- 5. xws = dinvp * (x_add@Wtop + x_max@Wbot), K=256 bf16-A MFMA ----
    gemm_mfma_bfA<<<(KC + 63) / 64, 256, 0, stream>>>((const uint4*)Fadd, (const uint4*)Fmax,
                                                      wpackK, dinvp,
                                                      (unsigned short*)Cbf, KC);

    // ---- 6. aprime(xws) + hp, all gathers (bf16 payloads) ----
    zn_gather<<<(N + 15) / 16, 256, 0, stream>>>(iqoffs, qslots, (const uint4*)Cbf,
                                                 (uint4*)Abf, N);            // Abf = zn
    edge_gather_plain<<<(N + 3) / 4, 256, 0, stream>>>(ieoffs, (const long long*)epack,
                                                       (const uint4*)Abf,
                                                       (uint4*)Hbf, N);      // Hbf = ye
    aphp_gather<<<(KC + 15) / 16, 256, 0, stream>>>(ipoffs, pslots, (const uint4*)Hbf,
                                                    (const uint4*)Cbf, dinvp, bblk,
                                                    (uint4*)Fadd, KC);       // Fadd = hp

    // ---- 7. cluster pools of hp + head ----
    seg_pool_bf<<<512, 128, 0, stream>>>((const unsigned short*)Fadd, cbatch, z, KC, 256, 384);
    head_kernel<<<Bq, 128, 0, stream>>>(z, cc, gma, bta, bmean, bvar, W1, b1, W2, b2, out);
}

// Round 15
// 470.989 us; speedup vs baseline: 1.0045x; 1.0045x over previous
//
#include <hip/hip_runtime.h>

// ---------------------------------------------------------------------------
// KPlexPool: GCN -> pools -> matrix-free pooled GCN -> MLP head + softmax
// Sizes: N=100000, E=1600000, F_IN=128, H=128, M=150000, KC=60000, B=64
// R4: scatter-atomics -> device-built CSR gathers.
// R5/R9: bf16 payloads for all re-read intermediates (fp32 accum).
// R7: dense GEMMs -> bf16 MFMA (prepacked W fragments).
// R8/R10/R11: two-level edge fill; class-private cursors; block-aggregated
//   claims (returning-atomic count was the wall).
// R12: quarter-wave row walks (16 lanes x uint4, 4 rows in flight/instr).
// R13/R14: (a) nontemporal stores for bf16-row outputs (via ext_vector u32x4
//   -- HIP uint4 is a struct and rejected by the builtin) + nt loads for
//   epack/slot streams. (b) GEMM epilogue via LDS -> u32x4 nt stores.
//   (c) node_scalars fused into fill_compact. (d) fill_pairs x2 merged.
// ---------------------------------------------------------------------------

#define H 128
#define TILE_AGG 2048
#define GRID_AGG 784     // %8==0; hist_coarse/fill_stage_agg MUST share this

typedef __attribute__((ext_vector_type(4))) float f32x4;
typedef __attribute__((ext_vector_type(8))) short bf16x8;
typedef __attribute__((ext_vector_type(4))) unsigned int u32x4;

__device__ __forceinline__ void atomAddF(float* p, float v) {
    unsafeAtomicAdd(p, v);   // global_atomic_add_f32 on gfx950
}
__device__ __forceinline__ void atomMaxPos(float* p, float v) {
    // valid for non-negative floats (bit pattern order == numeric order)
    atomicMax(reinterpret_cast<int*>(p), __float_as_int(v));
}

// bf16 helpers: RNE pack, shift unpack
__device__ __forceinline__ unsigned int bfr(float f) {
    unsigned int u = __float_as_uint(f);
    return (u + 0x7fffu + ((u >> 16) & 1u)) >> 16;
}
__device__ __forceinline__ unsigned int pk2(float lo, float hi) {
    return bfr(lo) | (bfr(hi) << 16);
}
__device__ __forceinline__ float unlo(unsigned int v) { return __uint_as_float(v << 16); }
__device__ __forceinline__ float unhi(unsigned int v) { return __uint_as_float(v & 0xffff0000u); }

__device__ __forceinline__ void ntstore4(unsigned int a, unsigned int b,
                                         unsigned int c, unsigned int d, void* p) {
    u32x4 v; v.x = a; v.y = b; v.z = c; v.w = d;
    __builtin_nontemporal_store(v, (u32x4*)p);
}

// ========================= CSR build (pairs) ===============================
__global__ void count_pairs(const int* __restrict__ a, const int* __restrict__ b,
                            int* __restrict__ ca, int* __restrict__ cb, int M) {
    int i = blockIdx.x * blockDim.x + threadIdx.x;
    if (i < M) {
        atomicAdd(&ca[__builtin_nontemporal_load(a + i)], 1);
        atomicAdd(&cb[__builtin_nontemporal_load(b + i)], 1);
    }
}

// exclusive scan of c[0..m) in place, 1024 elems/block (used for KC/N arrays)
__global__ __launch_bounds__(256) void scan_partial(const int* __restrict__ c,
                                                    int* __restrict__ part, int m) {
    __shared__ int red[4];
    int base = blockIdx.x * 1024, t = threadIdx.x;
    int s = 0;
    for (int j = t; j < 1024; j += 256) { int i = base + j; if (i < m) s += c[i]; }
    for (int o = 32; o; o >>= 1) s += __shfl_down(s, o, 64);
    if ((t & 63) == 0) red[t >> 6] = s;
    __syncthreads();
    if (t == 0) part[blockIdx.x] = red[0] + red[1] + red[2] + red[3];
}
__global__ void scan_spine(int* part, int G) {
    if (threadIdx.x == 0) {
        int acc = 0;
        for (int i = 0; i < G; ++i) { int v = part[i]; part[i] = acc; acc += v; }
    }
}
__global__ __launch_bounds__(256) void scan_apply(int* __restrict__ c,
                                                  const int* __restrict__ part, int m) {
    __shared__ int wsum[4];
    int base = blockIdx.x * 1024, t = threadIdx.x;
    int i0 = base + t * 4;
    int v0 = 0, v1 = 0, v2 = 0, v3 = 0;
    if (i0     < m) v0 = c[i0];
    if (i0 + 1 < m) v1 = c[i0 + 1];
    if (i0 + 2 < m) v2 = c[i0 + 2];
    if (i0 + 3 < m) v3 = c[i0 + 3];
    int ts = v0 + v1 + v2 + v3;
    int lane = t & 63, w = t >> 6;
    int sc = ts;
    for (int o = 1; o < 64; o <<= 1) { int u = __shfl_up(sc, o, 64); if (lane >= o) sc += u; }
    if (lane == 63) wsum[w] = sc;
    __syncthreads();
    int off = part[blockIdx.x];
    for (int k = 0; k < w; ++k) off += wsum[k];
    int ex = off + sc - ts;
    if (i0     < m) c[i0]     = ex;
    if (i0 + 1 < m) c[i0 + 1] = ex + v0;
    if (i0 + 2 < m) c[i0 + 2] = ex + v0 + v1;
    if (i0 + 3 < m) c[i0 + 3] = ex + v0 + v1 + v2;
}

// both pair CSRs in one pass: pslots (by cluster) + qslots (by node)
__global__ void fill_pairs_both(const int* __restrict__ cclus, const int* __restrict__ cnodes,
                                int* __restrict__ ipoffs, int* __restrict__ iqoffs,
                                int* __restrict__ pslots, int* __restrict__ qslots, int M) {
    int i = blockIdx.x * blockDim.x + threadIdx.x;
    if (i >= M) return;
    int c = __builtin_nontemporal_load(cclus + i);
    int n = __builtin_nontemporal_load(cnodes + i);
    int qp = atomicAdd(&ipoffs[c], 1);
    int qq = atomicAdd(&iqoffs[n], 1);
    pslots[qp] = n;
    qslots[qq] = c;
}

// qcnt[n] = pair count at node n (end-of-row convention offsets)
__global__ void qcnt_kernel(const int* __restrict__ qoffs, int* __restrict__ qcnt, int N) {
    int n = blockIdx.x * blockDim.x + threadIdx.x;
    if (n < N) qcnt[n] = qoffs[n] - (n ? qoffs[n - 1] : 0);
}

// ================= two-level edge fill (block-aggregated claims) ===========
// bucket = dst>>8 (256 nodes); xcd-class = blockIdx&7; cursors class-major
// [x*Ppad+b] (line-private per class). Both kernels iterate tiles with
// IDENTICAL tile->block mapping so counts and claims agree per (bucket,class).
__global__ __launch_bounds__(256) void hist_coarse(const int* __restrict__ dst,
                                                   int* __restrict__ histc, int E, int Ppad) {
    __shared__ int hb[512];   // P <= 512 buckets (N <= 131072)
    for (int i = threadIdx.x; i < 512; i += 256) hb[i] = 0;
    __syncthreads();
    int x = blockIdx.x & 7;
    for (int tile = blockIdx.x; (long)tile * TILE_AGG < E; tile += GRID_AGG) {
        int base = tile * TILE_AGG;
        int lim = min(TILE_AGG, E - base);
        for (int i = threadIdx.x; i < lim; i += 256)
            atomicAdd(&hb[__builtin_nontemporal_load(dst + base + i) >> 8], 1);
    }
    __syncthreads();
    for (int i = threadIdx.x; i < 512; i += 256)
        if (hb[i]) atomicAdd(&histc[x * Ppad + i], hb[i]);
}

// single-block scan over the (bucket,class) histogram (m = P*8 <= 4096):
// reads class-major histc, writes bucket-major exclusive starts (curscan)
// and a class-major copy (curw, the working cursors).
__global__ __launch_bounds__(1024) void scan_small(
    const int* __restrict__ histc, int* __restrict__ curscan,
    int* __restrict__ curw, int P, int Ppad)
{
    __shared__ int wtot[16];
    int t = threadIdx.x;
    int m = P * 8;
    int i0 = t * 4;
    int v[4];
#pragma unroll
    for (int k = 0; k < 4; ++k) {
        int id = i0 + k;
        v[k] = (id < m) ? histc[(id & 7) * Ppad + (id >> 3)] : 0;
    }
    int ts = v[0] + v[1] + v[2] + v[3];
    int lane = t & 63, w = t >> 6;
    int sc = ts;
    for (int o = 1; o < 64; o <<= 1) { int u = __shfl_up(sc, o, 64); if (lane >= o) sc += u; }
    if (lane == 63) wtot[w] = sc;
    __syncthreads();
    int off = 0;
    for (int k = 0; k < w; ++k) off += wtot[k];
    int ex = off + sc - ts;
#pragma unroll
    for (int k = 0; k < 4; ++k) {
        int id = i0 + k;
        if (id < m) {
            curscan[id] = ex;
            curw[(id & 7) * Ppad + (id >> 3)] = ex;
        }
        ex += v[k];
    }
}

// stage, block-aggregated: per 2048-edge tile, LDS bucket histogram ->
// ONE returning atomic per (bucket,tile) claims a contiguous run ->
// scatter each edge at gbase[b] + LDS-rank. dloc packed in src bits 20..27.
__global__ __launch_bounds__(256) void fill_stage_agg(
    const int* __restrict__ src, const int* __restrict__ dst,
    const float* __restrict__ w, int* __restrict__ cur,
    int2* __restrict__ stg, int E, int Ppad)
{
    __shared__ int cnt[512];
    __shared__ int gbase[512];
    int t = threadIdx.x;
    int x = blockIdx.x & 7;
    for (int tile = blockIdx.x; (long)tile * TILE_AGG < E; tile += GRID_AGG) {
        int base = tile * TILE_AGG;
        int lim = min(TILE_AGG, E - base);
        for (int i = t; i < 512; i += 256) cnt[i] = 0;
        __syncthreads();
        for (int i = t; i < lim; i += 256)
            atomicAdd(&cnt[__builtin_nontemporal_load(dst + base + i) >> 8], 1);
        __syncthreads();
        for (int b = t; b < 512; b += 256) {
            int c = cnt[b];
            if (c) gbase[b] = atomicAdd(&cur[x * Ppad + b], c);
        }
        __syncthreads();
        for (int i = t; i < 512; i += 256) cnt[i] = 0;
        __syncthreads();
        for (int i = t; i < lim; i += 256) {
            int d  = __builtin_nontemporal_load(dst + base + i);
            int s  = __builtin_nontemporal_load(src + base + i);
            float wv = __builtin_nontemporal_load(w + base + i);
            int b = d >> 8;
            int r = atomicAdd(&cnt[b], 1);
            stg[gbase[b] + r] = make_int2(s | ((d & 255) << 20), __float_as_int(wv));
        }
        __syncthreads();   // protect cnt/gbase before next tile's reset
    }
}

// compact: one block owns one bucket's contiguous region [gs,ge).
// FUSED node_scalars: accumulates degw and ye1 per node via LDS float
// atomics during the count pass (qcnt must be ready), writes dinv/ye1.
__global__ __launch_bounds__(1024) void fill_compact(
    const int* __restrict__ curscan, const int2* __restrict__ stg,
    int2* __restrict__ epack, int* __restrict__ ieoffs,
    const int* __restrict__ qcnt, float* __restrict__ dinv,
    float* __restrict__ ye1, int E, int N, int P)
{
    __shared__ int cnt[256];
    __shared__ float degw[256];
    __shared__ float ysum[256];
    __shared__ int wsum[4];
    int b = blockIdx.x, t = threadIdx.x;
    int gs = curscan[b * 8];
    int ge = (b == P - 1) ? E : curscan[(b + 1) * 8];
    if (t < 256) { cnt[t] = 0; degw[t] = 0.f; ysum[t] = 0.f; }
    __syncthreads();
    for (int i = gs + t; i < ge; i += 1024) {
        int2 pv = stg[i];
        int dloc = (pv.x >> 20) & 255;
        int s = pv.x & 0xFFFFF;
        float w = __int_as_float(pv.y);
        atomicAdd(&cnt[dloc], 1);
        atomicAdd(&degw[dloc], w);
        atomicAdd(&ysum[dloc], w * (float)qcnt[s]);
    }
    __syncthreads();
    int v = 0, sc = 0;
    if (t < 256) {                       // waves 0-3 entirely inside
        v = cnt[t];
        int lane = t & 63;
        sc = v;
        for (int o = 1; o < 64; o <<= 1) { int u = __shfl_up(sc, o, 64); if (lane >= o) sc += u; }
        if (lane == 63) wsum[t >> 6] = sc;
    }
    __syncthreads();
    if (t < 256) {
        int off = 0;
        for (int k = 0; k < (t >> 6); ++k) off += wsum[k];
        int excl = off + sc - v;         // exclusive prefix within bucket
        int node = b * 256 + t;
        if (node < N) {
            ieoffs[node] = gs + excl + v;   // end-of-row
            dinv[node] = rsqrtf(degw[t] + 1.0f);
            ye1[node] = ysum[t];
        }
        cnt[t] = excl;                   // reuse as per-node cursor
    }
    __syncthreads();
    for (int i = gs + t; i < ge; i += 1024) {
        int2 pv = stg[i];
        int pos = atomicAdd(&cnt[(pv.x >> 20) & 255], 1);
        epack[gs + pos] = make_int2(pv.x & 0xFFFFF, pv.y);
    }
}

__global__ void cluster_dinvp(const int* __restrict__ poffs, const int* __restrict__ pslots,
                              const float* __restrict__ ye1, float* __restrict__ dinvp, int KC) {
    int c = blockIdx.x * blockDim.x + threadIdx.x;
    if (c >= KC) return;
    int b = c ? poffs[c - 1] : 0, e = poffs[c];
    float s = 0.f;
    for (int i = b; i < e; ++i) s += ye1[pslots[i]];
    dinvp[c] = rsqrtf(s + 1.0f);
}

// ========================= MFMA GEMM (bf16 in, fp32 accum) =================
template <int KSTEPS>
__global__ void prepack_w(const float* __restrict__ W, uint4* __restrict__ wp) {
    int idx = blockIdx.x * blockDim.x + threadIdx.x;   // frag-lane id
    if (idx >= 8 * KSTEPS * 64) return;
    int l = idx & 63;
    int f = idx >> 6;                 // ct*KSTEPS + kb
    int kb = f % KSTEPS, ct = f / KSTEPS;
    int col = ct * 16 + (l & 15);
    int k0 = kb * 32 + (l >> 4) * 8;
    uint4 u;
    u.x = pk2(W[(k0 + 0) * 128 + col], W[(k0 + 1) * 128 + col]);
    u.y = pk2(W[(k0 + 2) * 128 + col], W[(k0 + 3) * 128 + col]);
    u.z = pk2(W[(k0 + 4) * 128 + col], W[(k0 + 5) * 128 + col]);
    u.w = pk2(W[(k0 + 6) * 128 + col], W[(k0 + 7) * 128 + col]);
    wp[idx] = u;
}

// shared epilogue: stage bf16 C-tile to LDS, cooperative u32x4 nt stores.
// Sl: ushort[64][128] (16KB) overlapping the W buffer (post-sync reuse).
__device__ __forceinline__ void gemm_epilogue(
    unsigned short* Sl, f32x4 (&acc)[8], const float* rowscale,
    unsigned short* outb, int nrows, int t, int l, int wv, int row0)
{
    int rbase = row0 + (l >> 4) * 4;
    float sc[4];
#pragma unroll
    for (int g = 0; g < 4; ++g)
        sc[g] = rowscale ? (rbase + g < nrows ? rowscale[rbase + g] : 1.f) : 1.f;
    int lr = wv * 16 + (l >> 4) * 4;   // local row base
#pragma unroll
    for (int ct = 0; ct < 8; ++ct) {
        int col = ct * 16 + (l & 15);
#pragma unroll
        for (int g = 0; g < 4; ++g)
            Sl[(lr + g) * 128 + col] = (unsigned short)bfr(acc[ct][g] * sc[g]);
    }
    __syncthreads();
    long rowbase = (long)(row0 - wv * 16);   // = blockIdx.x * 64
    u32x4* out4 = (u32x4*)outb;
    const u32x4* S4 = (const u32x4*)Sl;
    for (int idx = t; idx < 64 * 16; idx += 256) {
        long gr = rowbase + (idx >> 4);
        if (gr < nrows)
            __builtin_nontemporal_store(S4[idx], &out4[gr * 16 + (idx & 15)]);
    }
}

// fp32-A variant (used for x @ Win), bf16 out.
template <int KSTEPS>
__global__ __launch_bounds__(256) void gemm_mfma(
    const float* __restrict__ XA,
    const uint4* __restrict__ wpack, const float* __restrict__ rowscale,
    unsigned short* __restrict__ outb, int nrows)
{
    __shared__ uint4 Wl[8 * KSTEPS * 64];
    int t = threadIdx.x;
    for (int i = t; i < 8 * KSTEPS * 64; i += 256) Wl[i] = wpack[i];
    __syncthreads();

    int l = t & 63, wv = t >> 6;
    int row0 = blockIdx.x * 64 + wv * 16;
    int rr = row0 + (l & 15);
    long rc = (rr < nrows ? rr : nrows - 1);
    int kq = (l >> 4) * 8;

    f32x4 acc[8];
#pragma unroll
    for (int ct = 0; ct < 8; ++ct) acc[ct] = (f32x4)0.f;

#pragma unroll
    for (int kb = 0; kb < KSTEPS; ++kb) {
        const float* p = XA + rc * 128 + kb * 32 + kq;
        float4 a0 = ((const float4*)p)[0];
        float4 a1 = ((const float4*)p)[1];
        union { uint4 u; bf16x8 v; } af;
        af.u.x = pk2(a0.x, a0.y); af.u.y = pk2(a0.z, a0.w);
        af.u.z = pk2(a1.x, a1.y); af.u.w = pk2(a1.z, a1.w);
#pragma unroll
        for (int ct = 0; ct < 8; ++ct) {
            union { uint4 u; bf16x8 v; } bf;
            bf.u = Wl[(ct * KSTEPS + kb) * 64 + l];
            acc[ct] = __builtin_amdgcn_mfma_f32_16x16x32_bf16(af.v, bf.v, acc[ct], 0, 0, 0);
        }
    }
    __syncthreads();   // done with Wl; reuse as bf16 staging
    gemm_epilogue((unsigned short*)Wl, acc, rowscale, outb, nrows, t, l, wv, row0);
}

// bf16-A variant, K=256 over two bf16 matrices (xadd rows || xmax rows).
__global__ __launch_bounds__(256) void gemm_mfma_bfA(
    const uint4* __restrict__ XA, const uint4* __restrict__ XB,
    const uint4* __restrict__ wpack, const float* __restrict__ rowscale,
    unsigned short* __restrict__ outb, int nrows)
{
    __shared__ uint4 Wl[8 * 8 * 64];
    int t = threadIdx.x;
    for (int i = t; i < 4096; i += 256) Wl[i] = wpack[i];
    __syncthreads();

    int l = t & 63, wv = t >> 6;
    int row0 = blockIdx.x * 64 + wv * 16;
    int rr = row0 + (l & 15);
    long rc = (rr < nrows ? rr : nrows - 1);
    int kq8 = (l >> 4);            // kq/8, 0..3

    f32x4 acc[8];
#pragma unroll
    for (int ct = 0; ct < 8; ++ct) acc[ct] = (f32x4)0.f;

#pragma unroll
    for (int kb = 0; kb < 8; ++kb) {
        const uint4* s = (kb >= 4) ? XB : XA;
        union { uint4 u; bf16x8 v; } af;
        af.u = s[rc * 16 + (kb & 3) * 4 + kq8];   // bf16 row = 16 uint4
#pragma unroll
        for (int ct = 0; ct < 8; ++ct) {
            union { uint4 u; bf16x8 v; } bf;
            bf.u = Wl[(ct * 8 + kb) * 64 + l];
            acc[ct] = __builtin_amdgcn_mfma_f32_16x16x32_bf16(af.v, bf.v, acc[ct], 0, 0, 0);
        }
    }
    __syncthreads();
    gemm_epilogue((unsigned short*)Wl, acc, rowscale, outb, nrows, t, l, wv, row0);
}

// ========================= vector CSR gathers (quarter-wave) ===============
// bf16 row = 256B = 16 lanes x uint4; 4 edges in flight per load instr.

// GCN pass 1, fused: h[n] = relu(dinv_n*(sum w*dinv_s*xw[s] + dinv_n*xw[n]) + b)
__global__ __launch_bounds__(256) void gcn1_gather(
    const int* __restrict__ eoffs, const long long* __restrict__ epack,
    const float* __restrict__ dinv, const uint4* __restrict__ X4,
    const float* __restrict__ bin, uint4* __restrict__ H4, int N)
{
    int n = blockIdx.x * 4 + (threadIdx.x >> 6);
    if (n >= N) return;
    int lane = threadIdx.x & 63;
    int ql = lane & 15, grp = lane >> 4;
    int b = n ? eoffs[n - 1] : 0, e = eoffs[n];
    float4 a0 = make_float4(0.f, 0.f, 0.f, 0.f), a1 = a0;
    for (int i = b; i < e; i += 64) {
        int cnt = min(64, e - i);
        int s_l = 0; float sc_l = 0.f;
        if (lane < cnt) {
            long long pk8 = __builtin_nontemporal_load(epack + i + lane);
            s_l = (int)(pk8 & 0xffffffff);
            sc_l = __int_as_float((int)(pk8 >> 32)) * dinv[s_l];
        }
        int steps = (cnt + 3) >> 2;
#pragma unroll 2
        for (int j = 0; j < steps; ++j) {
            int idx = 4 * j + grp;            // sc==0 for idx>=cnt (tail)
            int s = __shfl(s_l, idx, 64);
            float sc = __shfl(sc_l, idx, 64);
            uint4 v = X4[(unsigned)s * 16u + ql];
            a0.x += sc * unlo(v.x); a0.y += sc * unhi(v.x);
            a0.z += sc * unlo(v.y); a0.w += sc * unhi(v.y);
            a1.x += sc * unlo(v.z); a1.y += sc * unhi(v.z);
            a1.z += sc * unlo(v.w); a1.w += sc * unhi(v.w);
        }
    }
#pragma unroll
    for (int o = 16; o <= 32; o <<= 1) {
        a0.x += __shfl_xor(a0.x, o, 64); a0.y += __shfl_xor(a0.y, o, 64);
        a0.z += __shfl_xor(a0.z, o, 64); a0.w += __shfl_xor(a0.w, o, 64);
        a1.x += __shfl_xor(a1.x, o, 64); a1.y += __shfl_xor(a1.y, o, 64);
        a1.z += __shfl_xor(a1.z, o, 64); a1.w += __shfl_xor(a1.w, o, 64);
    }
    if (grp == 0) {
        float dd = dinv[n];
        uint4 sv = X4[(unsigned)n * 16u + ql];
        float4 b0 = ((const float4*)bin)[ql * 2];
        float4 b1 = ((const float4*)bin)[ql * 2 + 1];
        float o0 = fmaxf(dd * (a0.x + dd * unlo(sv.x)) + b0.x, 0.f);
        float o1 = fmaxf(dd * (a0.y + dd * unhi(sv.x)) + b0.y, 0.f);
        float o2 = fmaxf(dd * (a0.z + dd * unlo(sv.y)) + b0.z, 0.f);
        float o3 = fmaxf(dd * (a0.w + dd * unhi(sv.y)) + b0.w, 0.f);
        float o4 = fmaxf(dd * (a1.x + dd * unlo(sv.z)) + b1.x, 0.f);
        float o5 = fmaxf(dd * (a1.y + dd * unhi(sv.z)) + b1.y, 0.f);
        float o6 = fmaxf(dd * (a1.z + dd * unlo(sv.w)) + b1.z, 0.f);
        float o7 = fmaxf(dd * (a1.w + dd * unhi(sv.w)) + b1.w, 0.f);
        ntstore4(pk2(o0, o1), pk2(o2, o3), pk2(o4, o5), pk2(o6, o7),
                 &H4[(long)n * 16 + ql]);
    }
}

// plain edge gather from bf16 rows: Out[n] = sum_e w * X[src]  (bf16 out)
__global__ __launch_bounds__(256) void edge_gather_plain(
    const int* __restrict__ eoffs, const long long* __restrict__ epack,
    const uint4* __restrict__ X4, uint4* __restrict__ Out4, int N)
{
    int n = blockIdx.x * 4 + (threadIdx.x >> 6);
    if (n >= N) return;
    int lane = threadIdx.x & 63;
    int ql = lane & 15, grp = lane >> 4;
    int b = n ? eoffs[n - 1] : 0, e = eoffs[n];
    float4 a0 = make_float4(0.f, 0.f, 0.f, 0.f), a1 = a0;
    for (int i = b; i < e; i += 64) {
        int cnt = min(64, e - i);
        int s_l = 0; float sc_l = 0.f;
        if (lane < cnt) {
            long long pk8 = __builtin_nontemporal_load(epack + i + lane);
            s_l = (int)(pk8 & 0xffffffff);
            sc_l = __int_as_float((int)(pk8 >> 32));
        }
        int steps = (cnt + 3) >> 2;
#pragma unroll 2
        for (int j = 0; j < steps; ++j) {
            int idx = 4 * j + grp;
            int s = __shfl(s_l, idx, 64);
            float sc = __shfl(sc_l, idx, 64);
            uint4 v = X4[(unsigned)s * 16u + ql];
            a0.x += sc * unlo(v.x); a0.y += sc * unhi(v.x);
            a0.z += sc * unlo(v.y); a0.w += sc * unhi(v.y);
            a1.x += sc * unlo(v.z); a1.y += sc * unhi(v.z);
            a1.z += sc * unlo(v.w); a1.w += sc * unhi(v.w);
        }
    }
#pragma unroll
    for (int o = 16; o <= 32; o <<= 1) {
        a0.x += __shfl_xor(a0.x, o, 64); a0.y += __shfl_xor(a0.y, o, 64);
        a0.z += __shfl_xor(a0.z, o, 64); a0.w += __shfl_xor(a0.w, o, 64);
        a1.x += __shfl_xor(a1.x, o, 64); a1.y += __shfl_xor(a1.y, o, 64);
        a1.z += __shfl_xor(a1.z, o, 64); a1.w += __shfl_xor(a1.w, o, 64);
    }
    if (grp == 0)
        ntstore4(pk2(a0.x, a0.y), pk2(a0.z, a0.w), pk2(a1.x, a1.y), pk2(a1.z, a1.w),
                 &Out4[(long)n * 16 + ql]);
}

// cover pool: x_add[c] = sum h[node], x_max[c] = max h[node]  (bf16 in/out)
__global__ __launch_bounds__(256) void cover_pool(
    const int* __restrict__ poffs, const int* __restrict__ pslots,
    const uint4* __restrict__ H4, uint4* __restrict__ xadd,
    uint4* __restrict__ xmax, int KC)
{
    int c = blockIdx.x * 16 + (threadIdx.x >> 4);
    if (c >= KC) return;
    int ql = threadIdx.x & 15;
    int b = c ? poffs[c - 1] : 0, e = poffs[c];
    float4 s0 = make_float4(0.f, 0.f, 0.f, 0.f), s1 = s0, m0 = s0, m1 = s0;
#pragma unroll 2
    for (int i = b; i < e; ++i) {
        uint4 v = H4[(unsigned)__builtin_nontemporal_load(pslots + i) * 16u + ql];
        float e0 = unlo(v.x), e1 = unhi(v.x), e2 = unlo(v.y), e3 = unhi(v.y);
        float e4 = unlo(v.z), e5 = unhi(v.z), e6 = unlo(v.w), e7 = unhi(v.w);
        s0.x += e0; s0.y += e1; s0.z += e2; s0.w += e3;
        s1.x += e4; s1.y += e5; s1.z += e6; s1.w += e7;
        m0.x = fmaxf(m0.x, e0); m0.y = fmaxf(m0.y, e1);
        m0.z = fmaxf(m0.z, e2); m0.w = fmaxf(m0.w, e3);
        m1.x = fmaxf(m1.x, e4); m1.y = fmaxf(m1.y, e5);
        m1.z = fmaxf(m1.z, e6); m1.w = fmaxf(m1.w, e7);
    }
    ntstore4(pk2(s0.x, s0.y), pk2(s0.z, s0.w), pk2(s1.x, s1.y), pk2(s1.z, s1.w),
             &xadd[(long)c * 16 + ql]);
    ntstore4(pk2(m0.x, m0.y), pk2(m0.z, m0.w), pk2(m1.x, m1.y), pk2(m1.z, m1.w),
             &xmax[(long)c * 16 + ql]);
}

// zn[n] = sum_{p at node n} xws[cluster_p]   (bf16 in/out, fp32 accum)
__global__ __launch_bounds__(256) void zn_gather(
    const int* __restrict__ qoffs, const int* __restrict__ qslots,
    const uint4* __restrict__ X4, uint4* __restrict__ Z4, int N)
{
    int n = blockIdx.x * 16 + (threadIdx.x >> 4);
    if (n >= N) return;
    int ql = threadIdx.x & 15;
    int b = n ? qoffs[n - 1] : 0, e = qoffs[n];
    float4 a0 = make_float4(0.f, 0.f, 0.f, 0.f), a1 = a0;
#pragma unroll 2
    for (int i = b; i < e; ++i) {
        uint4 v = X4[(unsigned)__builtin_nontemporal_load(qslots + i) * 16u + ql];
        a0.x += unlo(v.x); a0.y += unhi(v.x); a0.z += unlo(v.y); a0.w += unhi(v.y);
        a1.x += unlo(v.z); a1.y += unhi(v.z); a1.z += unlo(v.w); a1.w += unhi(v.w);
    }
    ntstore4(pk2(a0.x, a0.y), pk2(a0.z, a0.w), pk2(a1.x, a1.y), pk2(a1.z, a1.w),
             &Z4[(long)n * 16 + ql]);
}

// hp[c] = relu(dinvp_c * (sum_{p in c} ye[node_p] + xws[c]) + b_blk)
__global__ __launch_bounds__(256) void aphp_gather(
    const int* __restrict__ poffs, const int* __restrict__ pslots,
    const uint4* __restrict__ Y4, const uint4* __restrict__ xws4,
    const float* __restrict__ dinvp, const float* __restrict__ bblk,
    uint4* __restrict__ hp4, int KC)
{
    int c = blockIdx.x * 16 + (threadIdx.x >> 4);
    if (c >= KC) return;
    int ql = threadIdx.x & 15;
    int b = c ? poffs[c - 1] : 0, e = poffs[c];
    float4 a0 = make_float4(0.f, 0.f, 0.f, 0.f), a1 = a0;
#pragma unroll 2
    for (int i = b; i < e; ++i) {
        uint4 v = Y4[(unsigned)__builtin_nontemporal_load(pslots + i) * 16u + ql];
        a0.x += unlo(v.x); a0.y += unhi(v.x); a0.z += unlo(v.y); a0.w += unhi(v.y);
        a1.x += unlo(v.z); a1.y += unhi(v.z); a1.z += unlo(v.w); a1.w += unhi(v.w);
    }
    float d = dinvp[c];
    uint4 xv = xws4[(long)c * 16 + ql];
    float4 b0 = ((const float4*)bblk)[ql * 2];
    float4 b1 = ((const float4*)bblk)[ql * 2 + 1];
    float o0 = fmaxf(d * (a0.x + unlo(xv.x)) + b0.x, 0.f);
    float o1 = fmaxf(d * (a0.y + unhi(xv.x)) + b0.y, 0.f);
    float o2 = fmaxf(d * (a0.z + unlo(xv.y)) + b0.z, 0.f);
    float o3 = fmaxf(d * (a0.w + unhi(xv.y)) + b0.w, 0.f);
    float o4 = fmaxf(d * (a1.x + unlo(xv.z)) + b1.x, 0.f);
    float o5 = fmaxf(d * (a1.y + unhi(xv.z)) + b1.y, 0.f);
    float o6 = fmaxf(d * (a1.z + unlo(xv.w)) + b1.z, 0.f);
    float o7 = fmaxf(d * (a1.w + unhi(xv.w)) + b1.w, 0.f);
    ntstore4(pk2(o0, o1), pk2(o2, o3), pk2(o4, o5), pk2(o6, o7),
             &hp4[(long)c * 16 + ql]);
}

// ========================= batch pools + head ==============================
__global__ __launch_bounds__(128) void seg_pool_bf(
    const unsigned short* __restrict__ X, const int* __restrict__ seg,
    float* __restrict__ Z, int n, int sumoff, int maxoff)
{
    int j = threadIdx.x;
    long beg = (long)blockIdx.x * n / gridDim.x;
    long end = (long)(blockIdx.x + 1) * n / gridDim.x;
    if (beg >= end) return;
    int curb = seg[beg];
    float s = 0.f, mx = 0.f;
    for (long i = beg; i < end; ++i) {
        int b = seg[i];
        if (b != curb) {
            atomAddF(&Z[(long)curb * 512 + sumoff + j], s);
            atomMaxPos(&Z[(long)curb * 512 + maxoff + j], mx);
            s = 0.f; mx = 0.f; curb = b;
        }
        float v = __uint_as_float((unsigned int)X[i * (long)H + j] << 16);
        s += v; mx = fmaxf(mx, v);
    }
    atomAddF(&Z[(long)curb * 512 + sumoff + j], s);
    atomMaxPos(&Z[(long)curb * 512 + maxoff + j], mx);
}

__global__ void hist64(const int* __restrict__ seg, float* __restrict__ cc, int n) {
    __shared__ int hc[128];
    if (threadIdx.x < 128) hc[threadIdx.x] = 0;
    __syncthreads();
    for (int i = blockIdx.x * blockDim.x + threadIdx.x; i < n; i += gridDim.x * blockDim.x)
        atomicAdd(&hc[seg[i]], 1);
    __syncthreads();
    if (threadIdx.x < 128 && hc[threadIdx.x] != 0)
        atomAddF(&cc[threadIdx.x], (float)hc[threadIdx.x]);
}

__global__ __launch_bounds__(128) void head_kernel(
    const float* __restrict__ z, const float* __restrict__ cc,
    const float* __restrict__ gamma, const float* __restrict__ beta,
    const float* __restrict__ bmean, const float* __restrict__ bvar,
    const float* __restrict__ W1, const float* __restrict__ b1,
    const float* __restrict__ W2, const float* __restrict__ b2,
    float* __restrict__ out)
{
    __shared__ float zb[512];
    __shared__ float z1[128];
    __shared__ float lg[10];
    __shared__ float red[2];
    int b = blockIdx.x, t = threadIdx.x;
    float ccb = cc[b];
    for (int k = t; k < 512; k += 128) {
        float v = z[(long)b * 512 + k];
        if (k >= 256 && k < 384) v /= ccb;
        v = (v - bmean[k]) * rsqrtf(bvar[k] + 1e-5f) * gamma[k] + beta[k];
        zb[k] = v;
    }
    __syncthreads();
    float acc = b1[t];
    for (int k = 0; k < 512; ++k) acc += zb[k] * W1[k * 128 + t];
    z1[t] = fmaxf(acc, 0.f);
    __syncthreads();
    if (t < 10) {
        float a = b2[t];
        for (int k = 0; k < 128; ++k) a += z1[k] * W2[k * 10 + t];
        lg[t] = a;
    }
    __syncthreads();
    if (t == 0) {
        float m = lg[0];
        for (int i = 1; i < 10; ++i) m = fmaxf(m, lg[i]);
        float s = 0.f;
        for (int i = 0; i < 10; ++i) s += expf(lg[i] - m);
        red[0] = m; red[1] = s;
    }
    __syncthreads();
    if (t < 10) out[(long)b * 10 + t] = expf(lg[t] - red[0]) / red[1];
}

// ---------------------------------------------------------------------------
static void scan_ex(int* buf, int m, int* part, hipStream_t s) {
    int G = (m + 1023) / 1024;
    scan_partial<<<G, 256, 0, s>>>(buf, part, m);
    scan_spine<<<1, 64, 0, s>>>(part, G);
    scan_apply<<<G, 256, 0, s>>>(buf, part, m);
}

extern "C" void kernel_launch(void* const* d_in, const int* in_sizes, int n_in,
                              void* d_out, int out_size, void* d_ws, size_t ws_size,
                              hipStream_t stream)
{
    const float* x      = (const float*)d_in[0];
    const int*   ei     = (const int*)  d_in[1];
    const float* wts    = (const float*)d_in[2];
    const int*   batch  = (const int*)  d_in[3];
    const int*   cnodes = (const int*)  d_in[4];
    const int*   cclus  = (const int*)  d_in[5];
    const int*   cbatch = (const int*)  d_in[6];
    const float* Win    = (const float*)d_in[7];
    const float* bin    = (const float*)d_in[8];
    const float* Wblk   = (const float*)d_in[9];
    const float* bblk   = (const float*)d_in[10];
    const float* gma    = (const float*)d_in[11];
    const float* bta    = (const float*)d_in[12];
    const float* bmean  = (const float*)d_in[13];
    const float* bvar   = (const float*)d_in[14];
    const float* W1     = (const float*)d_in[15];
    const float* b1     = (const float*)d_in[16];
    const float* W2     = (const float*)d_in[17];
    const float* b2     = (const float*)d_in[18];
    float* out = (float*)d_out;

    const int N  = in_sizes[0] / H;
    const int E  = in_sizes[1] / 2;
    const int M  = in_sizes[4];
    const int KC = in_sizes[6];
    const int Bq = out_size / 10;
    const int P  = (N + 255) >> 8;       // coarse buckets (256 nodes), <=512
    const int Ppad = (P + 15) & ~15;     // class stride, whole 64B lines

    const int* src = ei;
    const int* dst = ei + E;

    const long NH = (long)N * H;
    const long KH = (long)KC * H;

    // ---- workspace layout (wpack first for 16B alignment) ----
    float* ws     = (float*)d_ws;
    uint4* wpackN = (uint4*)ws;                     // 2048 uint4 (32KB)
    uint4* wpackK = wpackN + 2048;                  // 4096 uint4 (64KB)
    unsigned int* Abf = (unsigned int*)(wpackK + 4096); // xw -> zn bf16 [NH/2]
    unsigned int* Hbf = Abf + NH / 2;               // h bf16 -> ye bf16 [NH/2]
    unsigned int* Cbf = Hbf + NH / 2;               // xws bf16          [KH/2]
    unsigned int* Fadd= Cbf + KH / 2;               // x_add bf16 -> hp  [KH/2]
    unsigned int* Fmax= Fadd + KH / 2;              // x_max bf16        [KH/2]
    float* dinv = (float*)(Fmax + KH / 2);          //                   [N]
    float* ye1  = dinv + N;                         //                   [N]
    float* dinvp= ye1 + N;                          //                   [KC]
    float* z    = dinvp + KC;                       // pooled features   [Bq*512]
    float* cc   = z + (long)Bq * 512;               // cluster counts    [Bq]
    int* ieoffs = (int*)(cc + Bq);    // edge CSR offsets (dst)  [N]
    int* ipoffs = ieoffs + N;         // pair CSR by cluster     [KC]
    int* iqoffs = ipoffs + KC;        // pair CSR by node        [N]
    int* epack  = iqoffs + N;         // {src, w} per edge slot  [2E]
    int* pslots = epack + 2L * E;     // node per cluster-slot   [M]
    int* qslots = pslots + M;         // cluster per node-slot   [M]
    int* spart  = qslots + M;         // scan partials           [2048]
    int* curscan= spart + 2048;       // bucket-major starts     [P*8]
    int* histc  = curscan + P * 8;    // class-major hist        [8*Ppad]
    int* curw   = histc + 8 * Ppad;   // class-major cursors     [8*Ppad]
    int* qcnt   = curw + 8 * Ppad;    // pairs per node          [N]
    int2* estg  = (int2*)(qcnt + N);  // staged edges            [E]

    // ---- 1. pair CSRs first (qcnt feeds the fused edge compact) ----
    hipMemsetAsync(ipoffs, 0, ((long)KC + N) * sizeof(int), stream);
    count_pairs<<<(M + 255) / 256, 256, 0, stream>>>(cclus, cnodes, ipoffs, iqoffs, M);
    scan_ex(ipoffs, KC, spart, stream);
    scan_ex(iqoffs, N, spart, stream);
    fill_pairs_both<<<(M + 255) / 256, 256, 0, stream>>>(cclus, cnodes, ipoffs, iqoffs,
                                                         pslots, qslots, M);
    qcnt_kernel<<<(N + 255) / 256, 256, 0, stream>>>(iqoffs, qcnt, N);

    // ---- 2. edge CSR: block-aggregated fill + fused node scalars ----
    hipMemsetAsync(histc, 0, 8 * Ppad * sizeof(int), stream);
    hist_coarse<<<GRID_AGG, 256, 0, stream>>>(dst, histc, E, Ppad);
    scan_small<<<1, 1024, 0, stream>>>(histc, curscan, curw, P, Ppad);
    fill_stage_agg<<<GRID_AGG, 256, 0, stream>>>(src, dst, wts, curw, estg, E, Ppad);
    fill_compact<<<P, 1024, 0, stream>>>(curscan, estg, (int2*)epack, ieoffs,
                                         qcnt, dinv, ye1, E, N, P);
    cluster_dinvp<<<(KC + 255) / 256, 256, 0, stream>>>(ipoffs, pslots, ye1, dinvp, KC);

    // ---- 0. prepack weights into MFMA fragment order (bf16) ----
    prepack_w<4><<<8, 256, 0, stream>>>(Win, wpackN);
    prepack_w<8><<<16, 256, 0, stream>>>(Wblk, wpackK);

    // ---- 3. conv_in (fused): xw = x@Win (bf16 MFMA), gather+relu -> h bf16 ----
    gemm_mfma<4><<<(N + 63) / 64, 256, 0, stream>>>(x, wpackN, nullptr,
                                                    (unsigned short*)Abf, N);
    gcn1_gather<<<(N + 3) / 4, 256, 0, stream>>>(ieoffs, (const long long*)epack, dinv,
                                                 (const uint4*)Abf, bin,
                                                 (uint4*)Hbf, N);

    // ---- 4. pools of h (bf16) ----
    hipMemsetAsync(z, 0, ((long)Bq * 512 + Bq) * sizeof(float), stream);
    cover_pool<<<(KC + 15) / 16, 256, 0, stream>>>(ipoffs, pslots, (const uint4*)Hbf,
                                                   (uint4*)Fadd, (uint4*)Fmax, KC);
    seg_pool_bf<<<1024, 128, 0, stream>>>((const unsigned short*)Hbf, batch, z, N, 0, 128);
    hist64<<<256, 256, 0, stream>>>(cbatch, cc, KC);

    // ---- 5. xws = dinvp * (x_add@Wtop + x_max@Wbot), K=256 bf16-A MFMA ----
    gemm_mfma_bfA<<<(KC + 63) / 64, 256, 0, stream>>>((const uint4*)Fadd, (const uint4*)Fmax,
                                                      wpackK, dinvp,
                                                      (unsigned short*)Cbf, KC);

    // ---- 6. aprime(xws) + hp, all gathers (bf16 payloads) ----
    zn_gather<<<(N + 15) / 16, 256, 0, stream>>>(iqoffs, qslots, (const uint4*)Cbf,
                                                 (uint4*)Abf, N);            // Abf = zn
    edge_gather_plain<<<(N + 3) / 4, 256, 0, stream>>>(ieoffs, (const long long*)epack,
                                                       (const uint4*)Abf,
                                                       (uint4*)Hbf, N);      // Hbf = ye
    aphp_gather<<<(KC + 15) / 16, 256, 0, stream>>>(ipoffs, pslots, (const uint4*)Hbf,
                                                    (const uint4*)Cbf, dinvp, bblk,
                                                    (uint4*)Fadd, KC);       // Fadd = hp

    // ---- 7. cluster pools of hp + head ----
    seg_pool_bf<<<512, 128, 0, stream>>>((const unsigned short*)Fadd, cbatch, z, KC, 256, 384);
    head_kernel<<<Bq, 128, 0, stream>>>(z, cc, gma, bta, bmean, bvar, W1, b1, W2, b2, out);
}

// Round 16
// 443.840 us; speedup vs baseline: 1.0659x; 1.0612x over previous
//
#include <hip/hip_runtime.h>

// ---------------------------------------------------------------------------
// KPlexPool: GCN -> pools -> matrix-free pooled GCN -> MLP head + softmax
// Sizes: N=100000, E=1600000, F_IN=128, H=128, M=150000, KC=60000, B=64
// R4: scatter-atomics -> device-built CSR gathers.
// R5/R9: bf16 payloads for all re-read intermediates (fp32 accum).
// R7: dense GEMMs -> bf16 MFMA (prepacked W fragments).
// R8/R10/R11: two-level edge fill; class-private cursors; block-aggregated
//   claims (returning-atomic count was the wall).
// R12: quarter-wave row walks (16 lanes x uint4, 4 rows in flight/instr).
// R13-R15: GEMM epilogue via LDS -> uint4 stores; node_scalars fused into
//   fill_compact; fill_pairs merged; nt loads for index streams.
// R16: REVERT nt-STORES (R15 regression): xw/h/xws/zn/ye/hp are
//   producer->consumer intermediates -- nt stores evicted them from L2 and
//   the consumers refetched from HBM (gcn1 69->73us, FETCH unchanged).
//   Cached stores restored; nt retained ONLY on single-use index streams.
// ---------------------------------------------------------------------------

#define H 128
#define TILE_AGG 2048
#define GRID_AGG 784     // %8==0; hist_coarse/fill_stage_agg MUST share this

typedef __attribute__((ext_vector_type(4))) float f32x4;
typedef __attribute__((ext_vector_type(8))) short bf16x8;

__device__ __forceinline__ void atomAddF(float* p, float v) {
    unsafeAtomicAdd(p, v);   // global_atomic_add_f32 on gfx950
}
__device__ __forceinline__ void atomMaxPos(float* p, float v) {
    // valid for non-negative floats (bit pattern order == numeric order)
    atomicMax(reinterpret_cast<int*>(p), __float_as_int(v));
}

// bf16 helpers: RNE pack, shift unpack
__device__ __forceinline__ unsigned int bfr(float f) {
    unsigned int u = __float_as_uint(f);
    return (u + 0x7fffu + ((u >> 16) & 1u)) >> 16;
}
__device__ __forceinline__ unsigned int pk2(float lo, float hi) {
    return bfr(lo) | (bfr(hi) << 16);
}
__device__ __forceinline__ float unlo(unsigned int v) { return __uint_as_float(v << 16); }
__device__ __forceinline__ float unhi(unsigned int v) { return __uint_as_float(v & 0xffff0000u); }

// cached 16B store (R16: intermediates must stay in L2 for their consumers)
__device__ __forceinline__ void st4(unsigned int a, unsigned int b,
                                    unsigned int c, unsigned int d, void* p) {
    *(uint4*)p = make_uint4(a, b, c, d);
}

// ========================= CSR build (pairs) ===============================
__global__ void count_pairs(const int* __restrict__ a, const int* __restrict__ b,
                            int* __restrict__ ca, int* __restrict__ cb, int M) {
    int i = blockIdx.x * blockDim.x + threadIdx.x;
    if (i < M) {
        atomicAdd(&ca[__builtin_nontemporal_load(a + i)], 1);
        atomicAdd(&cb[__builtin_nontemporal_load(b + i)], 1);
    }
}

// exclusive scan of c[0..m) in place, 1024 elems/block (used for KC/N arrays)
__global__ __launch_bounds__(256) void scan_partial(const int* __restrict__ c,
                                                    int* __restrict__ part, int m) {
    __shared__ int red[4];
    int base = blockIdx.x * 1024, t = threadIdx.x;
    int s = 0;
    for (int j = t; j < 1024; j += 256) { int i = base + j; if (i < m) s += c[i]; }
    for (int o = 32; o; o >>= 1) s += __shfl_down(s, o, 64);
    if ((t & 63) == 0) red[t >> 6] = s;
    __syncthreads();
    if (t == 0) part[blockIdx.x] = red[0] + red[1] + red[2] + red[3];
}
__global__ void scan_spine(int* part, int G) {
    if (threadIdx.x == 0) {
        int acc = 0;
        for (int i = 0; i < G; ++i) { int v = part[i]; part[i] = acc; acc += v; }
    }
}
__global__ __launch_bounds__(256) void scan_apply(int* __restrict__ c,
                                                  const int* __restrict__ part, int m) {
    __shared__ int wsum[4];
    int base = blockIdx.x * 1024, t = threadIdx.x;
    int i0 = base + t * 4;
    int v0 = 0, v1 = 0, v2 = 0, v3 = 0;
    if (i0     < m) v0 = c[i0];
    if (i0 + 1 < m) v1 = c[i0 + 1];
    if (i0 + 2 < m) v2 = c[i0 + 2];
    if (i0 + 3 < m) v3 = c[i0 + 3];
    int ts = v0 + v1 + v2 + v3;
    int lane = t & 63, w = t >> 6;
    int sc = ts;
    for (int o = 1; o < 64; o <<= 1) { int u = __shfl_up(sc, o, 64); if (lane >= o) sc += u; }
    if (lane == 63) wsum[w] = sc;
    __syncthreads();
    int off = part[blockIdx.x];
    for (int k = 0; k < w; ++k) off += wsum[k];
    int ex = off + sc - ts;
    if (i0     < m) c[i0]     = ex;
    if (i0 + 1 < m) c[i0 + 1] = ex + v0;
    if (i0 + 2 < m) c[i0 + 2] = ex + v0 + v1;
    if (i0 + 3 < m) c[i0 + 3] = ex + v0 + v1 + v2;
}

// both pair CSRs in one pass: pslots (by cluster) + qslots (by node)
__global__ void fill_pairs_both(const int* __restrict__ cclus, const int* __restrict__ cnodes,
                                int* __restrict__ ipoffs, int* __restrict__ iqoffs,
                                int* __restrict__ pslots, int* __restrict__ qslots, int M) {
    int i = blockIdx.x * blockDim.x + threadIdx.x;
    if (i >= M) return;
    int c = __builtin_nontemporal_load(cclus + i);
    int n = __builtin_nontemporal_load(cnodes + i);
    int qp = atomicAdd(&ipoffs[c], 1);
    int qq = atomicAdd(&iqoffs[n], 1);
    pslots[qp] = n;
    qslots[qq] = c;
}

// qcnt[n] = pair count at node n (end-of-row convention offsets)
__global__ void qcnt_kernel(const int* __restrict__ qoffs, int* __restrict__ qcnt, int N) {
    int n = blockIdx.x * blockDim.x + threadIdx.x;
    if (n < N) qcnt[n] = qoffs[n] - (n ? qoffs[n - 1] : 0);
}

// ================= two-level edge fill (block-aggregated claims) ===========
// bucket = dst>>8 (256 nodes); xcd-class = blockIdx&7; cursors class-major
// [x*Ppad+b] (line-private per class). Both kernels iterate tiles with
// IDENTICAL tile->block mapping so counts and claims agree per (bucket,class).
__global__ __launch_bounds__(256) void hist_coarse(const int* __restrict__ dst,
                                                   int* __restrict__ histc, int E, int Ppad) {
    __shared__ int hb[512];   // P <= 512 buckets (N <= 131072)
    for (int i = threadIdx.x; i < 512; i += 256) hb[i] = 0;
    __syncthreads();
    int x = blockIdx.x & 7;
    for (int tile = blockIdx.x; (long)tile * TILE_AGG < E; tile += GRID_AGG) {
        int base = tile * TILE_AGG;
        int lim = min(TILE_AGG, E - base);
        for (int i = threadIdx.x; i < lim; i += 256)
            atomicAdd(&hb[__builtin_nontemporal_load(dst + base + i) >> 8], 1);
    }
    __syncthreads();
    for (int i = threadIdx.x; i < 512; i += 256)
        if (hb[i]) atomicAdd(&histc[x * Ppad + i], hb[i]);
}

// single-block scan over the (bucket,class) histogram (m = P*8 <= 4096):
// reads class-major histc, writes bucket-major exclusive starts (curscan)
// and a class-major copy (curw, the working cursors).
__global__ __launch_bounds__(1024) void scan_small(
    const int* __restrict__ histc, int* __restrict__ curscan,
    int* __restrict__ curw, int P, int Ppad)
{
    __shared__ int wtot[16];
    int t = threadIdx.x;
    int m = P * 8;
    int i0 = t * 4;
    int v[4];
#pragma unroll
    for (int k = 0; k < 4; ++k) {
        int id = i0 + k;
        v[k] = (id < m) ? histc[(id & 7) * Ppad + (id >> 3)] : 0;
    }
    int ts = v[0] + v[1] + v[2] + v[3];
    int lane = t & 63, w = t >> 6;
    int sc = ts;
    for (int o = 1; o < 64; o <<= 1) { int u = __shfl_up(sc, o, 64); if (lane >= o) sc += u; }
    if (lane == 63) wtot[w] = sc;
    __syncthreads();
    int off = 0;
    for (int k = 0; k < w; ++k) off += wtot[k];
    int ex = off + sc - ts;
#pragma unroll
    for (int k = 0; k < 4; ++k) {
        int id = i0 + k;
        if (id < m) {
            curscan[id] = ex;
            curw[(id & 7) * Ppad + (id >> 3)] = ex;
        }
        ex += v[k];
    }
}

// stage, block-aggregated: per 2048-edge tile, LDS bucket histogram ->
// ONE returning atomic per (bucket,tile) claims a contiguous run ->
// scatter each edge at gbase[b] + LDS-rank. dloc packed in src bits 20..27.
__global__ __launch_bounds__(256) void fill_stage_agg(
    const int* __restrict__ src, const int* __restrict__ dst,
    const float* __restrict__ w, int* __restrict__ cur,
    int2* __restrict__ stg, int E, int Ppad)
{
    __shared__ int cnt[512];
    __shared__ int gbase[512];
    int t = threadIdx.x;
    int x = blockIdx.x & 7;
    for (int tile = blockIdx.x; (long)tile * TILE_AGG < E; tile += GRID_AGG) {
        int base = tile * TILE_AGG;
        int lim = min(TILE_AGG, E - base);
        for (int i = t; i < 512; i += 256) cnt[i] = 0;
        __syncthreads();
        for (int i = t; i < lim; i += 256)
            atomicAdd(&cnt[__builtin_nontemporal_load(dst + base + i) >> 8], 1);
        __syncthreads();
        for (int b = t; b < 512; b += 256) {
            int c = cnt[b];
            if (c) gbase[b] = atomicAdd(&cur[x * Ppad + b], c);
        }
        __syncthreads();
        for (int i = t; i < 512; i += 256) cnt[i] = 0;
        __syncthreads();
        for (int i = t; i < lim; i += 256) {
            int d  = __builtin_nontemporal_load(dst + base + i);
            int s  = __builtin_nontemporal_load(src + base + i);
            float wv = __builtin_nontemporal_load(w + base + i);
            int b = d >> 8;
            int r = atomicAdd(&cnt[b], 1);
            stg[gbase[b] + r] = make_int2(s | ((d & 255) << 20), __float_as_int(wv));
        }
        __syncthreads();   // protect cnt/gbase before next tile's reset
    }
}

// compact: one block owns one bucket's contiguous region [gs,ge).
// FUSED node_scalars: accumulates degw and ye1 per node via LDS float
// atomics during the count pass (qcnt must be ready), writes dinv/ye1.
__global__ __launch_bounds__(1024) void fill_compact(
    const int* __restrict__ curscan, const int2* __restrict__ stg,
    int2* __restrict__ epack, int* __restrict__ ieoffs,
    const int* __restrict__ qcnt, float* __restrict__ dinv,
    float* __restrict__ ye1, int E, int N, int P)
{
    __shared__ int cnt[256];
    __shared__ float degw[256];
    __shared__ float ysum[256];
    __shared__ int wsum[4];
    int b = blockIdx.x, t = threadIdx.x;
    int gs = curscan[b * 8];
    int ge = (b == P - 1) ? E : curscan[(b + 1) * 8];
    if (t < 256) { cnt[t] = 0; degw[t] = 0.f; ysum[t] = 0.f; }
    __syncthreads();
    for (int i = gs + t; i < ge; i += 1024) {
        int2 pv = stg[i];
        int dloc = (pv.x >> 20) & 255;
        int s = pv.x & 0xFFFFF;
        float w = __int_as_float(pv.y);
        atomicAdd(&cnt[dloc], 1);
        atomicAdd(&degw[dloc], w);
        atomicAdd(&ysum[dloc], w * (float)qcnt[s]);
    }
    __syncthreads();
    int v = 0, sc = 0;
    if (t < 256) {                       // waves 0-3 entirely inside
        v = cnt[t];
        int lane = t & 63;
        sc = v;
        for (int o = 1; o < 64; o <<= 1) { int u = __shfl_up(sc, o, 64); if (lane >= o) sc += u; }
        if (lane == 63) wsum[t >> 6] = sc;
    }
    __syncthreads();
    if (t < 256) {
        int off = 0;
        for (int k = 0; k < (t >> 6); ++k) off += wsum[k];
        int excl = off + sc - v;         // exclusive prefix within bucket
        int node = b * 256 + t;
        if (node < N) {
            ieoffs[node] = gs + excl + v;   // end-of-row
            dinv[node] = rsqrtf(degw[t] + 1.0f);
            ye1[node] = ysum[t];
        }
        cnt[t] = excl;                   // reuse as per-node cursor
    }
    __syncthreads();
    for (int i = gs + t; i < ge; i += 1024) {
        int2 pv = stg[i];
        int pos = atomicAdd(&cnt[(pv.x >> 20) & 255], 1);
        epack[gs + pos] = make_int2(pv.x & 0xFFFFF, pv.y);
    }
}

__global__ void cluster_dinvp(const int* __restrict__ poffs, const int* __restrict__ pslots,
                              const float* __restrict__ ye1, float* __restrict__ dinvp, int KC) {
    int c = blockIdx.x * blockDim.x + threadIdx.x;
    if (c >= KC) return;
    int b = c ? poffs[c - 1] : 0, e = poffs[c];
    float s = 0.f;
    for (int i = b; i < e; ++i) s += ye1[pslots[i]];
    dinvp[c] = rsqrtf(s + 1.0f);
}

// ========================= MFMA GEMM (bf16 in, fp32 accum) =================
template <int KSTEPS>
__global__ void prepack_w(const float* __restrict__ W, uint4* __restrict__ wp) {
    int idx = blockIdx.x * blockDim.x + threadIdx.x;   // frag-lane id
    if (idx >= 8 * KSTEPS * 64) return;
    int l = idx & 63;
    int f = idx >> 6;                 // ct*KSTEPS + kb
    int kb = f % KSTEPS, ct = f / KSTEPS;
    int col = ct * 16 + (l & 15);
    int k0 = kb * 32 + (l >> 4) * 8;
    uint4 u;
    u.x = pk2(W[(k0 + 0) * 128 + col], W[(k0 + 1) * 128 + col]);
    u.y = pk2(W[(k0 + 2) * 128 + col], W[(k0 + 3) * 128 + col]);
    u.z = pk2(W[(k0 + 4) * 128 + col], W[(k0 + 5) * 128 + col]);
    u.w = pk2(W[(k0 + 6) * 128 + col], W[(k0 + 7) * 128 + col]);
    wp[idx] = u;
}

// shared epilogue: stage bf16 C-tile to LDS, cooperative uint4 stores.
// Sl: ushort[64][128] (16KB) overlapping the W buffer (post-sync reuse).
__device__ __forceinline__ void gemm_epilogue(
    unsigned short* Sl, f32x4 (&acc)[8], const float* rowscale,
    unsigned short* outb, int nrows, int t, int l, int wv, int row0)
{
    int rbase = row0 + (l >> 4) * 4;
    float sc[4];
#pragma unroll
    for (int g = 0; g < 4; ++g)
        sc[g] = rowscale ? (rbase + g < nrows ? rowscale[rbase + g] : 1.f) : 1.f;
    int lr = wv * 16 + (l >> 4) * 4;   // local row base
#pragma unroll
    for (int ct = 0; ct < 8; ++ct) {
        int col = ct * 16 + (l & 15);
#pragma unroll
        for (int g = 0; g < 4; ++g)
            Sl[(lr + g) * 128 + col] = (unsigned short)bfr(acc[ct][g] * sc[g]);
    }
    __syncthreads();
    long rowbase = (long)(row0 - wv * 16);   // = blockIdx.x * 64
    uint4* out4 = (uint4*)outb;
    const uint4* S4 = (const uint4*)Sl;
    for (int idx = t; idx < 64 * 16; idx += 256) {
        long gr = rowbase + (idx >> 4);
        if (gr < nrows)
            out4[gr * 16 + (idx & 15)] = S4[idx];
    }
}

// fp32-A variant (used for x @ Win), bf16 out.
template <int KSTEPS>
__global__ __launch_bounds__(256) void gemm_mfma(
    const float* __restrict__ XA,
    const uint4* __restrict__ wpack, const float* __restrict__ rowscale,
    unsigned short* __restrict__ outb, int nrows)
{
    __shared__ uint4 Wl[8 * KSTEPS * 64];
    int t = threadIdx.x;
    for (int i = t; i < 8 * KSTEPS * 64; i += 256) Wl[i] = wpack[i];
    __syncthreads();

    int l = t & 63, wv = t >> 6;
    int row0 = blockIdx.x * 64 + wv * 16;
    int rr = row0 + (l & 15);
    long rc = (rr < nrows ? rr : nrows - 1);
    int kq = (l >> 4) * 8;

    f32x4 acc[8];
#pragma unroll
    for (int ct = 0; ct < 8; ++ct) acc[ct] = (f32x4)0.f;

#pragma unroll
    for (int kb = 0; kb < KSTEPS; ++kb) {
        const float* p = XA + rc * 128 + kb * 32 + kq;
        float4 a0 = ((const float4*)p)[0];
        float4 a1 = ((const float4*)p)[1];
        union { uint4 u; bf16x8 v; } af;
        af.u.x = pk2(a0.x, a0.y); af.u.y = pk2(a0.z, a0.w);
        af.u.z = pk2(a1.x, a1.y); af.u.w = pk2(a1.z, a1.w);
#pragma unroll
        for (int ct = 0; ct < 8; ++ct) {
            union { uint4 u; bf16x8 v; } bf;
            bf.u = Wl[(ct * KSTEPS + kb) * 64 + l];
            acc[ct] = __builtin_amdgcn_mfma_f32_16x16x32_bf16(af.v, bf.v, acc[ct], 0, 0, 0);
        }
    }
    __syncthreads();   // done with Wl; reuse as bf16 staging
    gemm_epilogue((unsigned short*)Wl, acc, rowscale, outb, nrows, t, l, wv, row0);
}

// bf16-A variant, K=256 over two bf16 matrices (xadd rows || xmax rows).
__global__ __launch_bounds__(256) void gemm_mfma_bfA(
    const uint4* __restrict__ XA, const uint4* __restrict__ XB,
    const uint4* __restrict__ wpack, const float* __restrict__ rowscale,
    unsigned short* __restrict__ outb, int nrows)
{
    __shared__ uint4 Wl[8 * 8 * 64];
    int t = threadIdx.x;
    for (int i = t; i < 4096; i += 256) Wl[i] = wpack[i];
    __syncthreads();

    int l = t & 63, wv = t >> 6;
    int row0 = blockIdx.x * 64 + wv * 16;
    int rr = row0 + (l & 15);
    long rc = (rr < nrows ? rr : nrows - 1);
    int kq8 = (l >> 4);            // kq/8, 0..3

    f32x4 acc[8];
#pragma unroll
    for (int ct = 0; ct < 8; ++ct) acc[ct] = (f32x4)0.f;

#pragma unroll
    for (int kb = 0; kb < 8; ++kb) {
        const uint4* s = (kb >= 4) ? XB : XA;
        union { uint4 u; bf16x8 v; } af;
        af.u = s[rc * 16 + (kb & 3) * 4 + kq8];   // bf16 row = 16 uint4
#pragma unroll
        for (int ct = 0; ct < 8; ++ct) {
            union { uint4 u; bf16x8 v; } bf;
            bf.u = Wl[(ct * 8 + kb) * 64 + l];
            acc[ct] = __builtin_amdgcn_mfma_f32_16x16x32_bf16(af.v, bf.v, acc[ct], 0, 0, 0);
        }
    }
    __syncthreads();
    gemm_epilogue((unsigned short*)Wl, acc, rowscale, outb, nrows, t, l, wv, row0);
}

// ========================= vector CSR gathers (quarter-wave) ===============
// bf16 row = 256B = 16 lanes x uint4; 4 edges in flight per load instr.

// GCN pass 1, fused: h[n] = relu(dinv_n*(sum w*dinv_s*xw[s] + dinv_n*xw[n]) + b)
__global__ __launch_bounds__(256) void gcn1_gather(
    const int* __restrict__ eoffs, const long long* __restrict__ epack,
    const float* __restrict__ dinv, const uint4* __restrict__ X4,
    const float* __restrict__ bin, uint4* __restrict__ H4, int N)
{
    int n = blockIdx.x * 4 + (threadIdx.x >> 6);
    if (n >= N) return;
    int lane = threadIdx.x & 63;
    int ql = lane & 15, grp = lane >> 4;
    int b = n ? eoffs[n - 1] : 0, e = eoffs[n];
    float4 a0 = make_float4(0.f, 0.f, 0.f, 0.f), a1 = a0;
    for (int i = b; i < e; i += 64) {
        int cnt = min(64, e - i);
        int s_l = 0; float sc_l = 0.f;
        if (lane < cnt) {
            long long pk8 = __builtin_nontemporal_load(epack + i + lane);
            s_l = (int)(pk8 & 0xffffffff);
            sc_l = __int_as_float((int)(pk8 >> 32)) * dinv[s_l];
        }
        int steps = (cnt + 3) >> 2;
#pragma unroll 2
        for (int j = 0; j < steps; ++j) {
            int idx = 4 * j + grp;            // sc==0 for idx>=cnt (tail)
            int s = __shfl(s_l, idx, 64);
            float sc = __shfl(sc_l, idx, 64);
            uint4 v = X4[(unsigned)s * 16u + ql];
            a0.x += sc * unlo(v.x); a0.y += sc * unhi(v.x);
            a0.z += sc * unlo(v.y); a0.w += sc * unhi(v.y);
            a1.x += sc * unlo(v.z); a1.y += sc * unhi(v.z);
            a1.z += sc * unlo(v.w); a1.w += sc * unhi(v.w);
        }
    }
#pragma unroll
    for (int o = 16; o <= 32; o <<= 1) {
        a0.x += __shfl_xor(a0.x, o, 64); a0.y += __shfl_xor(a0.y, o, 64);
        a0.z += __shfl_xor(a0.z, o, 64); a0.w += __shfl_xor(a0.w, o, 64);
        a1.x += __shfl_xor(a1.x, o, 64); a1.y += __shfl_xor(a1.y, o, 64);
        a1.z += __shfl_xor(a1.z, o, 64); a1.w += __shfl_xor(a1.w, o, 64);
    }
    if (grp == 0) {
        float dd = dinv[n];
        uint4 sv = X4[(unsigned)n * 16u + ql];
        float4 b0 = ((const float4*)bin)[ql * 2];
        float4 b1 = ((const float4*)bin)[ql * 2 + 1];
        float o0 = fmaxf(dd * (a0.x + dd * unlo(sv.x)) + b0.x, 0.f);
        float o1 = fmaxf(dd * (a0.y + dd * unhi(sv.x)) + b0.y, 0.f);
        float o2 = fmaxf(dd * (a0.z + dd * unlo(sv.y)) + b0.z, 0.f);
        float o3 = fmaxf(dd * (a0.w + dd * unhi(sv.y)) + b0.w, 0.f);
        float o4 = fmaxf(dd * (a1.x + dd * unlo(sv.z)) + b1.x, 0.f);
        float o5 = fmaxf(dd * (a1.y + dd * unhi(sv.z)) + b1.y, 0.f);
        float o6 = fmaxf(dd * (a1.z + dd * unlo(sv.w)) + b1.z, 0.f);
        float o7 = fmaxf(dd * (a1.w + dd * unhi(sv.w)) + b1.w, 0.f);
        st4(pk2(o0, o1), pk2(o2, o3), pk2(o4, o5), pk2(o6, o7),
            &H4[(long)n * 16 + ql]);
    }
}

// plain edge gather from bf16 rows: Out[n] = sum_e w * X[src]  (bf16 out)
__global__ __launch_bounds__(256) void edge_gather_plain(
    const int* __restrict__ eoffs, const long long* __restrict__ epack,
    const uint4* __restrict__ X4, uint4* __restrict__ Out4, int N)
{
    int n = blockIdx.x * 4 + (threadIdx.x >> 6);
    if (n >= N) return;
    int lane = threadIdx.x & 63;
    int ql = lane & 15, grp = lane >> 4;
    int b = n ? eoffs[n - 1] : 0, e = eoffs[n];
    float4 a0 = make_float4(0.f, 0.f, 0.f, 0.f), a1 = a0;
    for (int i = b; i < e; i += 64) {
        int cnt = min(64, e - i);
        int s_l = 0; float sc_l = 0.f;
        if (lane < cnt) {
            long long pk8 = __builtin_nontemporal_load(epack + i + lane);
            s_l = (int)(pk8 & 0xffffffff);
            sc_l = __int_as_float((int)(pk8 >> 32));
        }
        int steps = (cnt + 3) >> 2;
#pragma unroll 2
        for (int j = 0; j < steps; ++j) {
            int idx = 4 * j + grp;
            int s = __shfl(s_l, idx, 64);
            float sc = __shfl(sc_l, idx, 64);
            uint4 v = X4[(unsigned)s * 16u + ql];
            a0.x += sc * unlo(v.x); a0.y += sc * unhi(v.x);
            a0.z += sc * unlo(v.y); a0.w += sc * unhi(v.y);
            a1.x += sc * unlo(v.z); a1.y += sc * unhi(v.z);
            a1.z += sc * unlo(v.w); a1.w += sc * unhi(v.w);
        }
    }
#pragma unroll
    for (int o = 16; o <= 32; o <<= 1) {
        a0.x += __shfl_xor(a0.x, o, 64); a0.y += __shfl_xor(a0.y, o, 64);
        a0.z += __shfl_xor(a0.z, o, 64); a0.w += __shfl_xor(a0.w, o, 64);
        a1.x += __shfl_xor(a1.x, o, 64); a1.y += __shfl_xor(a1.y, o, 64);
        a1.z += __shfl_xor(a1.z, o, 64); a1.w += __shfl_xor(a1.w, o, 64);
    }
    if (grp == 0)
        st4(pk2(a0.x, a0.y), pk2(a0.z, a0.w), pk2(a1.x, a1.y), pk2(a1.z, a1.w),
            &Out4[(long)n * 16 + ql]);
}

// cover pool: x_add[c] = sum h[node], x_max[c] = max h[node]  (bf16 in/out)
__global__ __launch_bounds__(256) void cover_pool(
    const int* __restrict__ poffs, const int* __restrict__ pslots,
    const uint4* __restrict__ H4, uint4* __restrict__ xadd,
    uint4* __restrict__ xmax, int KC)
{
    int c = blockIdx.x * 16 + (threadIdx.x >> 4);
    if (c >= KC) return;
    int ql = threadIdx.x & 15;
    int b = c ? poffs[c - 1] : 0, e = poffs[c];
    float4 s0 = make_float4(0.f, 0.f, 0.f, 0.f), s1 = s0, m0 = s0, m1 = s0;
#pragma unroll 2
    for (int i = b; i < e; ++i) {
        uint4 v = H4[(unsigned)__builtin_nontemporal_load(pslots + i) * 16u + ql];
        float e0 = unlo(v.x), e1 = unhi(v.x), e2 = unlo(v.y), e3 = unhi(v.y);
        float e4 = unlo(v.z), e5 = unhi(v.z), e6 = unlo(v.w), e7 = unhi(v.w);
        s0.x += e0; s0.y += e1; s0.z += e2; s0.w += e3;
        s1.x += e4; s1.y += e5; s1.z += e6; s1.w += e7;
        m0.x = fmaxf(m0.x, e0); m0.y = fmaxf(m0.y, e1);
        m0.z = fmaxf(m0.z, e2); m0.w = fmaxf(m0.w, e3);
        m1.x = fmaxf(m1.x, e4); m1.y = fmaxf(m1.y, e5);
        m1.z = fmaxf(m1.z, e6); m1.w = fmaxf(m1.w, e7);
    }
    st4(pk2(s0.x, s0.y), pk2(s0.z, s0.w), pk2(s1.x, s1.y), pk2(s1.z, s1.w),
        &xadd[(long)c * 16 + ql]);
    st4(pk2(m0.x, m0.y), pk2(m0.z, m0.w), pk2(m1.x, m1.y), pk2(m1.z, m1.w),
        &xmax[(long)c * 16 + ql]);
}

// zn[n] = sum_{p at node n} xws[cluster_p]   (bf16 in/out, fp32 accum)
__global__ __launch_bounds__(256) void zn_gather(
    const int* __restrict__ qoffs, const int* __restrict__ qslots,
    const uint4* __restrict__ X4, uint4* __restrict__ Z4, int N)
{
    int n = blockIdx.x * 16 + (threadIdx.x >> 4);
    if (n >= N) return;
    int ql = threadIdx.x & 15;
    int b = n ? qoffs[n - 1] : 0, e = qoffs[n];
    float4 a0 = make_float4(0.f, 0.f, 0.f, 0.f), a1 = a0;
#pragma unroll 2
    for (int i = b; i < e; ++i) {
        uint4 v = X4[(unsigned)__builtin_nontemporal_load(qslots + i) * 16u + ql];
        a0.x += unlo(v.x); a0.y += unhi(v.x); a0.z += unlo(v.y); a0.w += unhi(v.y);
        a1.x += unlo(v.z); a1.y += unhi(v.z); a1.z += unlo(v.w); a1.w += unhi(v.w);
    }
    st4(pk2(a0.x, a0.y), pk2(a0.z, a0.w), pk2(a1.x, a1.y), pk2(a1.z, a1.w),
        &Z4[(long)n * 16 + ql]);
}

// hp[c] = relu(dinvp_c * (sum_{p in c} ye[node_p] + xws[c]) + b_blk)
__global__ __launch_bounds__(256) void aphp_gather(
    const int* __restrict__ poffs, const int* __restrict__ pslots,
    const uint4* __restrict__ Y4, const uint4* __restrict__ xws4,
    const float* __restrict__ dinvp, const float* __restrict__ bblk,
    uint4* __restrict__ hp4, int KC)
{
    int c = blockIdx.x * 16 + (threadIdx.x >> 4);
    if (c >= KC) return;
    int ql = threadIdx.x & 15;
    int b = c ? poffs[c - 1] : 0, e = poffs[c];
    float4 a0 = make_float4(0.f, 0.f, 0.f, 0.f), a1 = a0;
#pragma unroll 2
    for (int i = b; i < e; ++i) {
        uint4 v = Y4[(unsigned)__builtin_nontemporal_load(pslots + i) * 16u + ql];
        a0.x += unlo(v.x); a0.y += unhi(v.x); a0.z += unlo(v.y); a0.w += unhi(v.y);
        a1.x += unlo(v.z); a1.y += unhi(v.z); a1.z += unlo(v.w); a1.w += unhi(v.w);
    }
    float d = dinvp[c];
    uint4 xv = xws4[(long)c * 16 + ql];
    float4 b0 = ((const float4*)bblk)[ql * 2];
    float4 b1 = ((const float4*)bblk)[ql * 2 + 1];
    float o0 = fmaxf(d * (a0.x + unlo(xv.x)) + b0.x, 0.f);
    float o1 = fmaxf(d * (a0.y + unhi(xv.x)) + b0.y, 0.f);
    float o2 = fmaxf(d * (a0.z + unlo(xv.y)) + b0.z, 0.f);
    float o3 = fmaxf(d * (a0.w + unhi(xv.y)) + b0.w, 0.f);
    float o4 = fmaxf(d * (a1.x + unlo(xv.z)) + b1.x, 0.f);
    float o5 = fmaxf(d * (a1.y + unhi(xv.z)) + b1.y, 0.f);
    float o6 = fmaxf(d * (a1.z + unlo(xv.w)) + b1.z, 0.f);
    float o7 = fmaxf(d * (a1.w + unhi(xv.w)) + b1.w, 0.f);
    st4(pk2(o0, o1), pk2(o2, o3), pk2(o4, o5), pk2(o6, o7),
        &hp4[(long)c * 16 + ql]);
}

// ========================= batch pools + head ==============================
__global__ __launch_bounds__(128) void seg_pool_bf(
    const unsigned short* __restrict__ X, const int* __restrict__ seg,
    float* __restrict__ Z, int n, int sumoff, int maxoff)
{
    int j = threadIdx.x;
    long beg = (long)blockIdx.x * n / gridDim.x;
    long end = (long)(blockIdx.x + 1) * n / gridDim.x;
    if (beg >= end) return;
    int curb = seg[beg];
    float s = 0.f, mx = 0.f;
    for (long i = beg; i < end; ++i) {
        int b = seg[i];
        if (b != curb) {
            atomAddF(&Z[(long)curb * 512 + sumoff + j], s);
            atomMaxPos(&Z[(long)curb * 512 + maxoff + j], mx);
            s = 0.f; mx = 0.f; curb = b;
        }
        float v = __uint_as_float((unsigned int)X[i * (long)H + j] << 16);
        s += v; mx = fmaxf(mx, v);
    }
    atomAddF(&Z[(long)curb * 512 + sumoff + j], s);
    atomMaxPos(&Z[(long)curb * 512 + maxoff + j], mx);
}

__global__ void hist64(const int* __restrict__ seg, float* __restrict__ cc, int n) {
    __shared__ int hc[128];
    if (threadIdx.x < 128) hc[threadIdx.x] = 0;
    __syncthreads();
    for (int i = blockIdx.x * blockDim.x + threadIdx.x; i < n; i += gridDim.x * blockDim.x)
        atomicAdd(&hc[seg[i]], 1);
    __syncthreads();
    if (threadIdx.x < 128 && hc[threadIdx.x] != 0)
        atomAddF(&cc[threadIdx.x], (float)hc[threadIdx.x]);
}

__global__ __launch_bounds__(128) void head_kernel(
    const float* __restrict__ z, const float* __restrict__ cc,
    const float* __restrict__ gamma, const float* __restrict__ beta,
    const float* __restrict__ bmean, const float* __restrict__ bvar,
    const float* __restrict__ W1, const float* __restrict__ b1,
    const float* __restrict__ W2, const float* __restrict__ b2,
    float* __restrict__ out)
{
    __shared__ float zb[512];
    __shared__ float z1[128];
    __shared__ float lg[10];
    __shared__ float red[2];
    int b = blockIdx.x, t = threadIdx.x;
    float ccb = cc[b];
    for (int k = t; k < 512; k += 128) {
        float v = z[(long)b * 512 + k];
        if (k >= 256 && k < 384) v /= ccb;
        v = (v - bmean[k]) * rsqrtf(bvar[k] + 1e-5f) * gamma[k] + beta[k];
        zb[k] = v;
    }
    __syncthreads();
    float acc = b1[t];
    for (int k = 0; k < 512; ++k) acc += zb[k] * W1[k * 128 + t];
    z1[t] = fmaxf(acc, 0.f);
    __syncthreads();
    if (t < 10) {
        float a = b2[t];
        for (int k = 0; k < 128; ++k) a += z1[k] * W2[k * 10 + t];
        lg[t] = a;
    }
    __syncthreads();
    if (t == 0) {
        float m = lg[0];
        for (int i = 1; i < 10; ++i) m = fmaxf(m, lg[i]);
        float s = 0.f;
        for (int i = 0; i < 10; ++i) s += expf(lg[i] - m);
        red[0] = m; red[1] = s;
    }
    __syncthreads();
    if (t < 10) out[(long)b * 10 + t] = expf(lg[t] - red[0]) / red[1];
}

// ---------------------------------------------------------------------------
static void scan_ex(int* buf, int m, int* part, hipStream_t s) {
    int G = (m + 1023) / 1024;
    scan_partial<<<G, 256, 0, s>>>(buf, part, m);
    scan_spine<<<1, 64, 0, s>>>(part, G);
    scan_apply<<<G, 256, 0, s>>>(buf, part, m);
}

extern "C" void kernel_launch(void* const* d_in, const int* in_sizes, int n_in,
                              void* d_out, int out_size, void* d_ws, size_t ws_size,
                              hipStream_t stream)
{
    const float* x      = (const float*)d_in[0];
    const int*   ei     = (const int*)  d_in[1];
    const float* wts    = (const float*)d_in[2];
    const int*   batch  = (const int*)  d_in[3];
    const int*   cnodes = (const int*)  d_in[4];
    const int*   cclus  = (const int*)  d_in[5];
    const int*   cbatch = (const int*)  d_in[6];
    const float* Win    = (const float*)d_in[7];
    const float* bin    = (const float*)d_in[8];
    const float* Wblk   = (const float*)d_in[9];
    const float* bblk   = (const float*)d_in[10];
    const float* gma    = (const float*)d_in[11];
    const float* bta    = (const float*)d_in[12];
    const float* bmean  = (const float*)d_in[13];
    const float* bvar   = (const float*)d_in[14];
    const float* W1     = (const float*)d_in[15];
    const float* b1     = (const float*)d_in[16];
    const float* W2     = (const float*)d_in[17];
    const float* b2     = (const float*)d_in[18];
    float* out = (float*)d_out;

    const int N  = in_sizes[0] / H;
    const int E  = in_sizes[1] / 2;
    const int M  = in_sizes[4];
    const int KC = in_sizes[6];
    const int Bq = out_size / 10;
    const int P  = (N + 255) >> 8;       // coarse buckets (256 nodes), <=512
    const int Ppad = (P + 15) & ~15;     // class stride, whole 64B lines

    const int* src = ei;
    const int* dst = ei + E;

    const long NH = (long)N * H;
    const long KH = (long)KC * H;

    // ---- workspace layout (wpack first for 16B alignment) ----
    float* ws     = (float*)d_ws;
    uint4* wpackN = (uint4*)ws;                     // 2048 uint4 (32KB)
    uint4* wpackK = wpackN + 2048;                  // 4096 uint4 (64KB)
    unsigned int* Abf = (unsigned int*)(wpackK + 4096); // xw -> zn bf16 [NH/2]
    unsigned int* Hbf = Abf + NH / 2;               // h bf16 -> ye bf16 [NH/2]
    unsigned int* Cbf = Hbf + NH / 2;               // xws bf16          [KH/2]
    unsigned int* Fadd= Cbf + KH / 2;               // x_add bf16 -> hp  [KH/2]
    unsigned int* Fmax= Fadd + KH / 2;              // x_max bf16        [KH/2]
    float* dinv = (float*)(Fmax + KH / 2);          //                   [N]
    float* ye1  = dinv + N;                         //                   [N]
    float* dinvp= ye1 + N;                          //                   [KC]
    float* z    = dinvp + KC;                       // pooled features   [Bq*512]
    float* cc   = z + (long)Bq * 512;               // cluster counts    [Bq]
    int* ieoffs = (int*)(cc + Bq);    // edge CSR offsets (dst)  [N]
    int* ipoffs = ieoffs + N;         // pair CSR by cluster     [KC]
    int* iqoffs = ipoffs + KC;        // pair CSR by node        [N]
    int* epack  = iqoffs + N;         // {src, w} per edge slot  [2E]
    int* pslots = epack + 2L * E;     // node per cluster-slot   [M]
    int* qslots = pslots + M;         // cluster per node-slot   [M]
    int* spart  = qslots + M;         // scan partials           [2048]
    int* curscan= spart + 2048;       // bucket-major starts     [P*8]
    int* histc  = curscan + P * 8;    // class-major hist        [8*Ppad]
    int* curw   = histc + 8 * Ppad;   // class-major cursors     [8*Ppad]
    int* qcnt   = curw + 8 * Ppad;    // pairs per node          [N]
    int2* estg  = (int2*)(qcnt + N);  // staged edges            [E]

    // ---- 1. pair CSRs first (qcnt feeds the fused edge compact) ----
    hipMemsetAsync(ipoffs, 0, ((long)KC + N) * sizeof(int), stream);
    count_pairs<<<(M + 255) / 256, 256, 0, stream>>>(cclus, cnodes, ipoffs, iqoffs, M);
    scan_ex(ipoffs, KC, spart, stream);
    scan_ex(iqoffs, N, spart, stream);
    fill_pairs_both<<<(M + 255) / 256, 256, 0, stream>>>(cclus, cnodes, ipoffs, iqoffs,
                                                         pslots, qslots, M);
    qcnt_kernel<<<(N + 255) / 256, 256, 0, stream>>>(iqoffs, qcnt, N);

    // ---- 2. edge CSR: block-aggregated fill + fused node scalars ----
    hipMemsetAsync(histc, 0, 8 * Ppad * sizeof(int), stream);
    hist_coarse<<<GRID_AGG, 256, 0, stream>>>(dst, histc, E, Ppad);
    scan_small<<<1, 1024, 0, stream>>>(histc, curscan, curw, P, Ppad);
    fill_stage_agg<<<GRID_AGG, 256, 0, stream>>>(src, dst, wts, curw, estg, E, Ppad);
    fill_compact<<<P, 1024, 0, stream>>>(curscan, estg, (int2*)epack, ieoffs,
                                         qcnt, dinv, ye1, E, N, P);
    cluster_dinvp<<<(KC + 255) / 256, 256, 0, stream>>>(ipoffs, pslots, ye1, dinvp, KC);

    // ---- 0. prepack weights into MFMA fragment order (bf16) ----
    prepack_w<4><<<8, 256, 0, stream>>>(Win, wpackN);
    prepack_w<8><<<16, 256, 0, stream>>>(Wblk, wpackK);

    // ---- 3. conv_in (fused): xw = x@Win (bf16 MFMA), gather+relu -> h bf16 ----
    gemm_mfma<4><<<(N + 63) / 64, 256, 0, stream>>>(x, wpackN, nullptr,
                                                    (unsigned short*)Abf, N);
    gcn1_gather<<<(N + 3) / 4, 256, 0, stream>>>(ieoffs, (const long long*)epack, dinv,
                                                 (const uint4*)Abf, bin,
                                                 (uint4*)Hbf, N);

    // ---- 4. pools of h (bf16) ----
    hipMemsetAsync(z, 0, ((long)Bq * 512 + Bq) * sizeof(float), stream);
    cover_pool<<<(KC + 15) / 16, 256, 0, stream>>>(ipoffs, pslots, (const uint4*)Hbf,
                                                   (uint4*)Fadd, (uint4*)Fmax, KC);
    seg_pool_bf<<<1024, 128, 0, stream>>>((const unsigned short*)Hbf, batch, z, N, 0, 128);
    hist64<<<256, 256, 0, stream>>>(cbatch, cc, KC);

    // ---- 5. xws = dinvp * (x_add@Wtop + x_max@Wbot), K=256 bf16-A MFMA ----
    gemm_mfma_bfA<<<(KC + 63) / 64, 256, 0, stream>>>((const uint4*)Fadd, (const uint4*)Fmax,
                                                      wpackK, dinvp,
                                                      (unsigned short*)Cbf, KC);

    // ---- 6. aprime(xws) + hp, all gathers (bf16 payloads) ----
    zn_gather<<<(N + 15) / 16, 256, 0, stream>>>(iqoffs, qslots, (const uint4*)Cbf,
                                                 (uint4*)Abf, N);            // Abf = zn
    edge_gather_plain<<<(N + 3) / 4, 256, 0, stream>>>(ieoffs, (const long long*)epack,
                                                       (const uint4*)Abf,
                                                       (uint4*)Hbf, N);      // Hbf = ye
    aphp_gather<<<(KC + 15) / 16, 256, 0, stream>>>(ipoffs, pslots, (const uint4*)Hbf,
                                                    (const uint4*)Cbf, dinvp, bblk,
                                                    (uint4*)Fadd, KC);       // Fadd = hp

    // ---- 7. cluster pools of hp + head ----
    seg_pool_bf<<<512, 128, 0, stream>>>((const unsigned short*)Fadd, cbatch, z, KC, 256, 384);
    head_kernel<<<Bq, 128, 0, stream>>>(z, cc, gma, bta, bmean, bvar, W1, b1, W2, b2, out);
}